// Round 1
// baseline (452.063 us; speedup 1.0000x reference)
//
#include <hip/hip_runtime.h>

// ------------------------------------------------------------------
// EnTransformerBlock: N=512 nodes, V=8 vectors, F=128 feats, H=8 heads,
// FH=16, BESSEL=8, R_MAX=10. Dense all-pairs edges (s != r).
//
// ws layout (floats):
//   kn   @ 0        [512][128]
//   qn   @ 65536    [512][128]
//   vn   @ 131072   [512][128]
//   A4   @ 196608   [512][8][128]   (Wek folded with q, pre-divided by 4)
//   Lb   @ 720896   [512][512][8]   (q.k gram per head, pre-divided by 4)
// total = 2,818,048 floats = 11.27 MB
// ------------------------------------------------------------------

__global__ __launch_bounds__(128) void k_nodeprep(
    const float* __restrict__ feat, const float* __restrict__ Wq,
    const float* __restrict__ Wk, const float* __restrict__ Wv,
    const float* __restrict__ Wek, float* __restrict__ ws)
{
  const int r = blockIdx.x, j = threadIdx.x;
  __shared__ float fr[128];
  __shared__ float qL[128];
  fr[j] = feat[r*128 + j];
  __syncthreads();
  float aq = 0.f, ak = 0.f, av = 0.f;
#pragma unroll 4
  for (int i = 0; i < 128; ++i) {
    const float f = fr[i];
    aq = fmaf(f, Wq[i*128 + j], aq);
    ak = fmaf(f, Wk[i*128 + j], ak);
    av = fmaf(f, Wv[i*128 + j], av);
  }
  ws[65536  + r*128 + j] = aq;   // qn
  ws[0      + r*128 + j] = ak;   // kn
  ws[131072 + r*128 + j] = av;   // vn
  qL[j] = aq;
  __syncthreads();
  const float* wr = Wek + j*128;   // row m = j
#pragma unroll
  for (int h = 0; h < 8; ++h) {
    float acc = 0.f;
#pragma unroll
    for (int f = 0; f < 16; ++f)
      acc = fmaf(wr[16*h + f], qL[16*h + f], acc);
    ws[196608 + (r*8 + h)*128 + j] = acc * 0.25f;
  }
}

__global__ __launch_bounds__(512) void k_lbase(float* __restrict__ ws)
{
  const int r = blockIdx.x, s = threadIdx.x;
  __shared__ float qL[128];
  if (s < 128) qL[s] = ws[65536 + r*128 + s];
  __syncthreads();
  const float* knr = ws + s*128;
  float* Lb = ws + 720896 + (r*512 + s)*8;
#pragma unroll
  for (int h = 0; h < 8; ++h) {
    float acc = 0.f;
#pragma unroll
    for (int f = 0; f < 16; ++f)
      acc = fmaf(knr[16*h + f], qL[16*h + f], acc);
    Lb[h] = acc * 0.25f;
  }
}

// LDS float offsets inside k_edge
//   Et(w)  @ w*1152          [64][18]  (row rho = b*8+v), 4 waves
//   H1(w)  @ 4608 + w*2304   pair rows [64][36]; later aliased as H2 [16][132]
//   A4L    @ 13824           [8][132]
//   WgT    @ 14880           [8][132]
//   posR   @ 15936           [24]
//   mW     @ 15960 [4][8],  dW @ 15992 [4][8], scl @ 16024 [4][8]
//   Mh     @ 16056 [8],     Dh @ 16064 [8]
// merge aliases: BW[w] -> Et(w) (1024), snW[w] -> H1(w)+0 (128),
//   vW[w] -> H1(w)+128 (24), Bm -> 4864 (1024),
//   asBuf -> 7168, o1 -> 7296, o2 -> 7424
#define LDS_TOT 16072

__global__ __launch_bounds__(256) void k_edge(
    const float* __restrict__ pos, const float* __restrict__ feat,
    const float* __restrict__ We0, const float* __restrict__ be0,
    const float* __restrict__ We1, const float* __restrict__ be1,
    const float* __restrict__ Wev, const float* __restrict__ Wg,
    const float* __restrict__ Wo0, const float* __restrict__ bo0,
    const float* __restrict__ Wo1, const float* __restrict__ bo1,
    const float* __restrict__ Wo2, const float* __restrict__ bo2,
    const float* __restrict__ ws, float* __restrict__ out)
{
  __shared__ __align__(16) float L[LDS_TOT];
  const int tid = threadIdx.x;
  const int w = tid >> 6, l = tid & 63;
  const int r = blockIdx.x;
  const int h = l >> 3, mq = l & 7;

  const float* vnG = ws + 131072;
  const float* A4G = ws + 196608;
  const float* LbG = ws + 720896;

  for (int idx = tid; idx < 1024; idx += 256) {
    const int hh = idx >> 7, m = idx & 127;
    L[13824 + hh*132 + m] = A4G[(r*8 + hh)*128 + m];
  }
  for (int idx = tid; idx < 1024; idx += 256) {
    const int m = idx >> 3, v = idx & 7;
    L[14880 + v*132 + m] = Wg[idx];   // Wg[m*8+v] transposed
  }
  if (tid < 24) L[15936 + tid] = pos[r*24 + tid];
  __syncthreads();

  float* Et = L + w*1152;
  float* H1 = L + 4608 + w*2304;

  const float2 b0v = *(const float2*)(be0 + 2*l);
  const float2 b1v = *(const float2*)(be1 + 2*l);

  float mrun = -1e30f, drun = 0.f;
  float B0,B1,B2,B3,B4,B5,B6,B7,B8,B9,B10,B11,B12,B13,B14,B15;
  B0=B1=B2=B3=B4=B5=B6=B7=B8=B9=B10=B11=B12=B13=B14=B15=0.f;
  float sn0 = 0.f, sn1 = 0.f, avv = 0.f;

  for (int tile = w; tile < 32; tile += 4) {
    const int sbase = tile << 4;
    // ---- geometry: lane = (s8 = l>>3, v = l&7), 2 sub-iters ----
    {
      const int s8 = l >> 3, v = l & 7;
      const float prx = L[15936 + v*3 + 0];
      const float pry = L[15936 + v*3 + 1];
      const float prz = L[15936 + v*3 + 2];
#pragma unroll
      for (int sg = 0; sg < 2; ++sg) {
        const int sl = sg*8 + s8;
        const int s = sbase + sl;
        const float dx = pos[s*24 + v*3 + 0] - prx;
        const float dy = pos[s*24 + v*3 + 1] - pry;
        const float dz = pos[s*24 + v*3 + 2] - prz;
        const float len = sqrtf(fmaf(dx,dx, fmaf(dy,dy, fmaf(dz,dz, 1e-20f))));
        const float y = 2.f - len*0.2f;
        const float env = (y > 0.f) ? 1.9784655648f * __expf(-1.f/y) : 0.f;
        const float coef = 0.4472135955f * env / len;
        const float arg = len * 0.31415926535f;   // pi/10
#pragma unroll
        for (int b = 0; b < 8; ++b)
          Et[(b*8 + v)*18 + sl] = coef * __sinf(arg * (float)(b + 1));
      }
    }
    asm volatile("s_waitcnt lgkmcnt(0)" ::: "memory");

    // ---- L0: e_scal[64] @ We0[64x128], cols j=2l,2l+1, 16 senders ----
    float a0[16], a1[16];
#pragma unroll
    for (int k = 0; k < 16; ++k) { a0[k] = 0.f; a1[k] = 0.f; }
#pragma unroll 4
    for (int rho = 0; rho < 64; ++rho) {
      const int i = ((rho & 7) << 3) | (rho >> 3);   // e_scal index v*8+b
      const float2 wv = *(const float2*)(We0 + i*128 + 2*l);
      const float* er = Et + rho*18;
#pragma unroll
      for (int u = 0; u < 8; ++u) {
        const float2 e2 = *(const float2*)(er + 2*u);
        a0[2*u]   = fmaf(e2.x, wv.x, a0[2*u]);
        a1[2*u]   = fmaf(e2.x, wv.y, a1[2*u]);
        a0[2*u+1] = fmaf(e2.y, wv.x, a0[2*u+1]);
        a1[2*u+1] = fmaf(e2.y, wv.y, a1[2*u+1]);
      }
    }
#pragma unroll
    for (int k = 0; k < 16; ++k) {
      const float z0 = a0[k] + b0v.x, z1 = a1[k] + b0v.y;
      const float g0 = z0 / (1.f + __expf(-z0));
      const float g1 = z1 / (1.f + __expf(-z1));
      *(float2*)(H1 + l*36 + 2*k) = make_float2(g0, g1);
    }
    asm volatile("s_waitcnt lgkmcnt(0)" ::: "memory");

    // ---- L1: h1[128] @ We1[128x128] ----
    float c0[16], c1[16];
#pragma unroll
    for (int k = 0; k < 16; ++k) { c0[k] = 0.f; c1[k] = 0.f; }
#pragma unroll 4
    for (int t = 0; t < 64; ++t) {
      const float2 wA = *(const float2*)(We1 + (2*t)*128 + 2*l);
      const float2 wB = *(const float2*)(We1 + (2*t+1)*128 + 2*l);
      const float* hr = H1 + t*36;
#pragma unroll
      for (int u = 0; u < 8; ++u) {
        const float4 q = *(const float4*)(hr + 4*u);
        c0[2*u]   += q.x*wA.x + q.y*wB.x;
        c1[2*u]   += q.x*wA.y + q.y*wB.y;
        c0[2*u+1] += q.z*wA.x + q.w*wB.x;
        c1[2*u+1] += q.z*wA.y + q.w*wB.y;
      }
    }
    asm volatile("s_waitcnt lgkmcnt(0)" ::: "memory");
#pragma unroll
    for (int k = 0; k < 16; ++k) {
      const float z0 = c0[k] + b1v.x, z1 = c1[k] + b1v.y;
      const float g0 = z0 / (1.f + __expf(-z0));
      const float g1 = z1 / (1.f + __expf(-z1));
      *(float2*)(H1 + k*132 + 2*l) = make_float2(g0, g1);   // H2 alias [16][132]
    }
    asm volatile("s_waitcnt lgkmcnt(0)" ::: "memory");

    // ---- per-sender: logits (A-contract + Lbase), gate, online softmax ----
    for (int sl = 0; sl < 16; ++sl) {
      const int s = sbase + sl;
      const float* hb = H1 + sl*132 + 4*mq;       // lane's m-set: 4*mq + 32k + j
      const float4 x0 = *(const float4*)(hb + 0);
      const float4 x1 = *(const float4*)(hb + 32);
      const float4 x2 = *(const float4*)(hb + 64);
      const float4 x3 = *(const float4*)(hb + 96);
      const float* ab = L + 13824 + h*132 + 4*mq;
      const float4 A0 = *(const float4*)(ab + 0);
      const float4 A1 = *(const float4*)(ab + 32);
      const float4 A2 = *(const float4*)(ab + 64);
      const float4 A3 = *(const float4*)(ab + 96);
      float p = x0.x*A0.x + x0.y*A0.y + x0.z*A0.z + x0.w*A0.w
              + x1.x*A1.x + x1.y*A1.y + x1.z*A1.z + x1.w*A1.w
              + x2.x*A2.x + x2.y*A2.y + x2.z*A2.z + x2.w*A2.w
              + x3.x*A3.x + x3.y*A3.y + x3.z*A3.z + x3.w*A3.w;
      p += __shfl_xor(p, 1, 8);
      p += __shfl_xor(p, 2, 8);
      p += __shfl_xor(p, 4, 8);
      const float* gb = L + 14880 + h*132 + 4*mq;
      const float4 G0 = *(const float4*)(gb + 0);
      const float4 G1 = *(const float4*)(gb + 32);
      const float4 G2 = *(const float4*)(gb + 64);
      const float4 G3 = *(const float4*)(gb + 96);
      float g = x0.x*G0.x + x0.y*G0.y + x0.z*G0.z + x0.w*G0.w
              + x1.x*G1.x + x1.y*G1.y + x1.z*G1.z + x1.w*G1.w
              + x2.x*G2.x + x2.y*G2.y + x2.z*G2.z + x2.w*G2.w
              + x3.x*G3.x + x3.y*G3.y + x3.z*G3.z + x3.w*G3.w;
      g += __shfl_xor(g, 1, 8);
      g += __shfl_xor(g, 2, 8);
      g += __shfl_xor(g, 4, 8);

      const bool valid = (s != r);
      float logit = p + LbG[(r*512 + s)*8 + h];
      if (!valid) logit = -1e30f;
      const float mn   = fmaxf(mrun, logit);
      const float resc = __expf(mrun - mn);
      const float wgt  = valid ? __expf(logit - mn) : 0.f;
      mrun = mn;
      drun = fmaf(drun, resc, wgt);
      B0  = fmaf(B0,  resc, wgt*x0.x); B1  = fmaf(B1,  resc, wgt*x0.y);
      B2  = fmaf(B2,  resc, wgt*x0.z); B3  = fmaf(B3,  resc, wgt*x0.w);
      B4  = fmaf(B4,  resc, wgt*x1.x); B5  = fmaf(B5,  resc, wgt*x1.y);
      B6  = fmaf(B6,  resc, wgt*x1.z); B7  = fmaf(B7,  resc, wgt*x1.w);
      B8  = fmaf(B8,  resc, wgt*x2.x); B9  = fmaf(B9,  resc, wgt*x2.y);
      B10 = fmaf(B10, resc, wgt*x2.z); B11 = fmaf(B11, resc, wgt*x2.w);
      B12 = fmaf(B12, resc, wgt*x3.x); B13 = fmaf(B13, resc, wgt*x3.y);
      B14 = fmaf(B14, resc, wgt*x3.z); B15 = fmaf(B15, resc, wgt*x3.w);
      const float2 vn2 = *(const float2*)(vnG + s*128 + 2*l);
      sn0 = fmaf(sn0, resc, wgt*vn2.x);
      sn1 = fmaf(sn1, resc, wgt*vn2.y);
      if (mq < 3) {
        const float dx = pos[s*24 + h*3 + 0] - L[15936 + h*3 + 0];
        const float dy = pos[s*24 + h*3 + 1] - L[15936 + h*3 + 1];
        const float dz = pos[s*24 + h*3 + 2] - L[15936 + h*3 + 2];
        const float len = sqrtf(fmaf(dx,dx, fmaf(dy,dy, fmaf(dz,dz, 1e-20f))));
        const float uc = (mq == 0 ? dx : (mq == 1 ? dy : dz)) / len;
        avv = fmaf(avv, resc, wgt * g * uc);
      }
    }
  }

  // ---- write per-wave partial state ----
  {
    float* BW = L + w*1152 + h*128 + 4*mq;
    *(float4*)(BW + 0)  = make_float4(B0,B1,B2,B3);
    *(float4*)(BW + 32) = make_float4(B4,B5,B6,B7);
    *(float4*)(BW + 64) = make_float4(B8,B9,B10,B11);
    *(float4*)(BW + 96) = make_float4(B12,B13,B14,B15);
    float* snW = L + 4608 + w*2304;
    snW[2*l]   = sn0;
    snW[2*l+1] = sn1;
    if (mq < 3) snW[128 + h*3 + mq] = avv;
    if (mq == 0) { L[15960 + w*8 + h] = mrun; L[15992 + w*8 + h] = drun; }
  }
  __syncthreads();

  // ---- merge softmax states across the 4 waves ----
  if (tid < 8) {
    const int hh = tid;
    float M = -1e30f;
#pragma unroll
    for (int ww = 0; ww < 4; ++ww) M = fmaxf(M, L[15960 + ww*8 + hh]);
    float D = 0.f;
#pragma unroll
    for (int ww = 0; ww < 4; ++ww) {
      const float sc = __expf(L[15960 + ww*8 + hh] - M);
      L[16024 + ww*8 + hh] = sc;
      D = fmaf(sc, L[15992 + ww*8 + hh], D);
    }
    L[16056 + hh] = M;
    L[16064 + hh] = D;
  }
  __syncthreads();
  // merged B -> Bm @4864
  for (int idx = tid; idx < 1024; idx += 256) {
    const int hh = idx >> 7, m = idx & 127;
    float acc = 0.f;
#pragma unroll
    for (int ww = 0; ww < 4; ++ww)
      acc = fmaf(L[16024 + ww*8 + hh], L[ww*1152 + hh*128 + m], acc);
    L[4864 + idx] = acc;
  }
  // equivariant output
  if (tid >= 192 && tid < 216) {
    const int t = tid - 192, v = t / 3;
    float acc = 0.f;
#pragma unroll
    for (int ww = 0; ww < 4; ++ww)
      acc = fmaf(L[16024 + ww*8 + v], L[4608 + ww*2304 + 128 + t], acc);
    out[r*24 + t] = pos[r*24 + t] + 1.7320508076f * acc / L[16064 + v];
  }
  __syncthreads();

  // agg_s = (sn_merged + Bm @ Wev) / D  -> asBuf @7168
  if (tid < 128) {
    const int j = tid, hh = j >> 4;
    float acc = 0.f;
#pragma unroll
    for (int ww = 0; ww < 4; ++ww)
      acc = fmaf(L[16024 + ww*8 + hh], L[4608 + ww*2304 + j], acc);
    float ev = 0.f;
    const float* Bmr = L + 4864 + hh*128;
#pragma unroll 4
    for (int m = 0; m < 128; ++m)
      ev = fmaf(Bmr[m], Wev[m*128 + j], ev);
    L[7168 + j] = (acc + ev) / L[16064 + hh];
  }
  __syncthreads();
  if (tid < 128) {
    const int j = tid;
    float acc = bo0[j];
#pragma unroll 4
    for (int i = 0; i < 128; ++i) acc = fmaf(L[7168 + i], Wo0[i*128 + j], acc);
    L[7296 + j] = acc / (1.f + __expf(-acc));
  }
  __syncthreads();
  if (tid < 128) {
    const int j = tid;
    float acc = bo1[j];
#pragma unroll 4
    for (int i = 0; i < 128; ++i) acc = fmaf(L[7296 + i], Wo1[i*128 + j], acc);
    L[7424 + j] = acc / (1.f + __expf(-acc));
  }
  __syncthreads();
  if (tid < 128) {
    const int j = tid;
    float acc = bo2[j];
#pragma unroll 4
    for (int i = 0; i < 128; ++i) acc = fmaf(L[7424 + i], Wo2[i*128 + j], acc);
    out[12288 + r*128 + j] = feat[r*128 + j] + acc;
  }
}

extern "C" void kernel_launch(void* const* d_in, const int* in_sizes, int n_in,
                              void* d_out, int out_size, void* d_ws, size_t ws_size,
                              hipStream_t stream)
{
  const float* pos  = (const float*)d_in[0];
  const float* feat = (const float*)d_in[1];
  const float* We0  = (const float*)d_in[2];
  const float* be0  = (const float*)d_in[3];
  const float* We1  = (const float*)d_in[4];
  const float* be1  = (const float*)d_in[5];
  const float* Wq   = (const float*)d_in[6];
  const float* Wk   = (const float*)d_in[7];
  const float* Wek  = (const float*)d_in[8];
  const float* Wv   = (const float*)d_in[9];
  const float* Wev  = (const float*)d_in[10];
  const float* Wg   = (const float*)d_in[11];
  const float* Wo0  = (const float*)d_in[12];
  const float* bo0  = (const float*)d_in[13];
  const float* Wo1  = (const float*)d_in[14];
  const float* bo1  = (const float*)d_in[15];
  const float* Wo2  = (const float*)d_in[16];
  const float* bo2  = (const float*)d_in[17];
  float* ws  = (float*)d_ws;
  float* out = (float*)d_out;

  hipLaunchKernelGGL(k_nodeprep, dim3(512), dim3(128), 0, stream,
                     feat, Wq, Wk, Wv, Wek, ws);
  hipLaunchKernelGGL(k_lbase, dim3(512), dim3(512), 0, stream, ws);
  hipLaunchKernelGGL(k_edge, dim3(512), dim3(256), 0, stream,
                     pos, feat, We0, be0, We1, be1, Wev, Wg,
                     Wo0, bo0, Wo1, bo1, Wo2, bo2, ws, out);
}

// Round 2
// 210.202 us; speedup vs baseline: 2.1506x; 2.1506x over previous
//
#include <hip/hip_runtime.h>

// EnTransformerBlock, MFMA edition. N=512, V=8, F=128, H=8, FH=16, VH=1, B=8.
// Dense all-pairs edges. All GEMM-shaped work on mfma_f32_16x16x32_bf16.
//
// ws layout (float offsets):
//   kn    @ 0         f32 [512][128]
//   qn    @ 65536     f32 [512][128]
//   Lb    @ 131072    f32 [512][512][8]   (q.k per head, pre-divided by 4)
//   vnT   @ 2228224   bf16[128][512]      (feat@Wv transposed)
//   AWgT  @ 2260992   bf16[512][16][128]  (rows 0-7: Wek-folded-q /4; 8-15: Wg^T)
//   W0T   @ 2785280   bf16[128][64]       (We0 transposed)
//   W1T   @ 2789376   bf16[128][128]      (We1 transposed)
// end 2797568 floats = 11.19 MB

#define WS_KN   0
#define WS_QN   65536
#define WS_LB   131072
#define WS_VNT  2228224
#define WS_AWGT 2260992
#define WS_W0T  2785280
#define WS_W1T  2789376

typedef short bf16x8 __attribute__((ext_vector_type(8)));
typedef short short4v __attribute__((ext_vector_type(4)));
typedef float f32x4 __attribute__((ext_vector_type(4)));

static __device__ __forceinline__ unsigned short f2b(float x) {
  union { float f; unsigned u; } c; c.f = x;
  unsigned r = c.u + 0x7fffu + ((c.u >> 16) & 1u);
  return (unsigned short)(r >> 16);
}
static __device__ __forceinline__ float fsilu(float x) {
  return x / (1.f + __expf(-x));
}

__global__ __launch_bounds__(128) void k_nodeprep(
    const float* __restrict__ feat, const float* __restrict__ Wq,
    const float* __restrict__ Wk, const float* __restrict__ Wv,
    const float* __restrict__ Wek, const float* __restrict__ Wg,
    float* __restrict__ ws)
{
  const int r = blockIdx.x, j = threadIdx.x;
  __shared__ float fr[128];
  __shared__ float qL[128];
  fr[j] = feat[r*128 + j];
  __syncthreads();
  float aq = 0.f, ak = 0.f, av = 0.f;
#pragma unroll 4
  for (int i = 0; i < 128; ++i) {
    const float f = fr[i];
    aq = fmaf(f, Wq[i*128 + j], aq);
    ak = fmaf(f, Wk[i*128 + j], ak);
    av = fmaf(f, Wv[i*128 + j], av);
  }
  ws[WS_QN + r*128 + j] = aq;
  ws[WS_KN + r*128 + j] = ak;
  unsigned short* vnT = (unsigned short*)(ws + WS_VNT);
  vnT[j*512 + r] = f2b(av);
  qL[j] = aq;
  __syncthreads();
  unsigned short* AW = (unsigned short*)(ws + WS_AWGT) + r*2048;
  const float* wr = Wek + j*128;
#pragma unroll
  for (int h = 0; h < 8; ++h) {
    float acc = 0.f;
#pragma unroll
    for (int f = 0; f < 16; ++f)
      acc = fmaf(wr[16*h + f], qL[16*h + f], acc);
    AW[h*128 + j] = f2b(acc * 0.25f);
  }
#pragma unroll
  for (int v = 0; v < 8; ++v)
    AW[(8 + v)*128 + j] = f2b(Wg[j*8 + v]);
}

__global__ __launch_bounds__(512) void k_lbase(float* __restrict__ ws)
{
  const int r = blockIdx.x, s = threadIdx.x;
  __shared__ float qL[128];
  if (s < 128) qL[s] = ws[WS_QN + r*128 + s];
  __syncthreads();
  const float* knr = ws + WS_KN + s*128;
  float* Lb = ws + WS_LB + (r*512 + s)*8;
#pragma unroll
  for (int h = 0; h < 8; ++h) {
    float acc = 0.f;
#pragma unroll
    for (int f = 0; f < 16; ++f)
      acc = fmaf(knr[16*h + f], qL[16*h + f], acc);
    Lb[h] = acc * 0.25f;
  }
}

__global__ __launch_bounds__(256) void k_wprep(
    const float* __restrict__ We0, const float* __restrict__ We1,
    float* __restrict__ ws)
{
  const int i = blockIdx.x*256 + threadIdx.x;
  unsigned short* W0T = (unsigned short*)(ws + WS_W0T);
  unsigned short* W1T = (unsigned short*)(ws + WS_W1T);
  if (i < 8192) {
    const int n = i >> 6, k = i & 63;
    W0T[n*64 + k] = f2b(We0[k*128 + n]);
  } else if (i < 24576) {
    const int t = i - 8192, n = t >> 7, k = t & 127;
    W1T[n*128 + k] = f2b(We1[k*128 + n]);
  }
}

// per-wave LDS (bytes from wave base, WSTR=14976):
//   H1   @ 0      bf16[16][136]  (4352)
//   Es   @ 4352   bf16[16][72]   (2304)   } H2 aliases Es region
//   H2   @ 4352   bf16[16][136]  (4352)   }
//   H2t  @ 8704   bf16[128][16]  (4096)
//   uC   @ 12800  bf16[32][16]   (1024)
//   wT   @ 13824  bf16[16][32]   (1024)
//   resp @ 14848  f32[8]
// merge buffers alias from 0 after __syncthreads.
#define WSTR 14976

#define MFMA(a,b,c) __builtin_amdgcn_mfma_f32_16x16x32_bf16((a),(b),(c),0,0,0)

__global__ __launch_bounds__(256, 2) void k_edge2(
    const float* __restrict__ pos, const float* __restrict__ feat,
    const float* __restrict__ be0, const float* __restrict__ be1,
    const float* __restrict__ Wev,
    const float* __restrict__ Wo0, const float* __restrict__ bo0,
    const float* __restrict__ Wo1, const float* __restrict__ bo1,
    const float* __restrict__ Wo2, const float* __restrict__ bo2,
    const float* __restrict__ ws, float* __restrict__ out)
{
  __shared__ __align__(16) char Lds[59904];
  const int tid = threadIdx.x;
  const int w = tid >> 6, l = tid & 63;
  const int r = blockIdx.x;
  const int c = l & 15, g = l >> 4;

  char* Wb = Lds + w*WSTR;
  unsigned short* H1  = (unsigned short*)(Wb);
  unsigned short* Es  = (unsigned short*)(Wb + 4352);
  unsigned short* H2  = (unsigned short*)(Wb + 4352);
  unsigned short* H2t = (unsigned short*)(Wb + 8704);
  unsigned short* uC  = (unsigned short*)(Wb + 12800);
  unsigned short* wT  = (unsigned short*)(Wb + 13824);
  float* resp = (float*)(Wb + 14848);

  const unsigned short* vnT = (const unsigned short*)(ws + WS_VNT);
  const unsigned short* AWg = (const unsigned short*)(ws + WS_AWGT) + r*2048;
  const unsigned short* W0T = (const unsigned short*)(ws + WS_W0T);
  const unsigned short* W1T = (const unsigned short*)(ws + WS_W1T);
  const float* Lb = ws + WS_LB + r*4096;

  // pre-zero pad regions (uC rows 24-31; wT cols 16-31)
  for (int idx = l; idx < 128; idx += 64)
    uC[(24 + (idx >> 4))*16 + (idx & 15)] = 0;
  for (int idx = l; idx < 256; idx += 64)
    wT[(idx >> 4)*32 + 16 + (idx & 15)] = 0;

  // preload biases (column c of each ntile) and AWg B-frags (r-fixed)
  float be0v[8], be1v[8];
#pragma unroll
  for (int nt = 0; nt < 8; ++nt) { be0v[nt] = be0[nt*16 + c]; be1v[nt] = be1[nt*16 + c]; }
  bf16x8 awf[4];
#pragma unroll
  for (int kb = 0; kb < 4; ++kb)
    awf[kb] = *(const bf16x8*)(AWg + c*128 + kb*32 + g*8);

  const int gv = l & 7, gs8 = l >> 3;
  const float prx = pos[r*24 + gv*3 + 0];
  const float pry = pos[r*24 + gv*3 + 1];
  const float prz = pos[r*24 + gv*3 + 2];

  f32x4 bh[8], sna[8], av2[2];
#pragma unroll
  for (int nt = 0; nt < 8; ++nt) { bh[nt] = (f32x4){0,0,0,0}; sna[nt] = (f32x4){0,0,0,0}; }
  av2[0] = (f32x4){0,0,0,0}; av2[1] = (f32x4){0,0,0,0};
  float mrun = -1e30f, drun = 0.f;

  for (int tile = w; tile < 32; tile += 4) {
    const int sbase = tile << 4;

    // ---- geometry: radial bessel*envelope -> Es, units -> uC ----
#pragma unroll
    for (int sg = 0; sg < 2; ++sg) {
      const int sl = sg*8 + gs8;
      const int s = sbase + sl;
      const float dx = pos[s*24 + gv*3 + 0] - prx;
      const float dy = pos[s*24 + gv*3 + 1] - pry;
      const float dz = pos[s*24 + gv*3 + 2] - prz;
      const float l2 = fmaf(dx,dx, fmaf(dy,dy, fmaf(dz,dz, 1e-20f)));
      const float inv = rsqrtf(l2);
      const float len = l2 * inv;
      uC[(gv*3+0)*16 + sl] = f2b(dx*inv);
      uC[(gv*3+1)*16 + sl] = f2b(dy*inv);
      uC[(gv*3+2)*16 + sl] = f2b(dz*inv);
      const float yy = 2.f - len*0.2f;
      const float env = (yy > 0.f) ? 1.9784655648f * __expf(-1.f/yy) : 0.f;
      const float coef = 0.4472135955f * env * inv;
      const float arg = len * 0.31415926535f;
      const float s1 = __sinf(arg), c1 = __cosf(arg);
      const float twc = 2.f*c1;
      bf16x8 ev;
      float sp = 0.f, sc = s1;
#pragma unroll
      for (int b = 0; b < 8; ++b) {
        ev[b] = (short)f2b(coef*sc);
        const float nx = fmaf(twc, sc, -sp);
        sp = sc; sc = nx;
      }
      *(bf16x8*)(Es + sl*72 + gv*8) = ev;
    }
    asm volatile("s_waitcnt lgkmcnt(0)" ::: "memory");

    // ---- L0: Es[16][64] @ We0 -> H1 ----
    {
      const bf16x8 af0 = *(const bf16x8*)(Es + c*72 + g*8);
      const bf16x8 af1 = *(const bf16x8*)(Es + c*72 + 32 + g*8);
      f32x4 h1a[8];
#pragma unroll
      for (int nt = 0; nt < 8; ++nt) {
        f32x4 acc = (f32x4){0,0,0,0};
        acc = MFMA(af0, *(const bf16x8*)(W0T + (nt*16+c)*64 + g*8), acc);
        acc = MFMA(af1, *(const bf16x8*)(W0T + (nt*16+c)*64 + 32 + g*8), acc);
        h1a[nt] = acc;
      }
#pragma unroll
      for (int nt = 0; nt < 8; ++nt) {
#pragma unroll
        for (int i = 0; i < 4; ++i)
          H1[(g*4+i)*136 + nt*16 + c] = f2b(fsilu(h1a[nt][i] + be0v[nt]));
      }
    }
    asm volatile("s_waitcnt lgkmcnt(0)" ::: "memory");

    // ---- L1: H1[16][128] @ We1 -> H2 (row-major + transposed) ----
    {
      bf16x8 a1[4];
#pragma unroll
      for (int kb = 0; kb < 4; ++kb)
        a1[kb] = *(const bf16x8*)(H1 + c*136 + kb*32 + g*8);
      f32x4 h2a[8];
#pragma unroll
      for (int nt = 0; nt < 8; ++nt) {
        f32x4 acc = (f32x4){0,0,0,0};
#pragma unroll
        for (int kb = 0; kb < 4; ++kb)
          acc = MFMA(a1[kb], *(const bf16x8*)(W1T + (nt*16+c)*128 + kb*32 + g*8), acc);
        h2a[nt] = acc;
      }
#pragma unroll
      for (int nt = 0; nt < 8; ++nt) {
        float v0 = fsilu(h2a[nt][0] + be1v[nt]);
        float v1 = fsilu(h2a[nt][1] + be1v[nt]);
        float v2 = fsilu(h2a[nt][2] + be1v[nt]);
        float v3 = fsilu(h2a[nt][3] + be1v[nt]);
        H2[(g*4+0)*136 + nt*16 + c] = f2b(v0);
        H2[(g*4+1)*136 + nt*16 + c] = f2b(v1);
        H2[(g*4+2)*136 + nt*16 + c] = f2b(v2);
        H2[(g*4+3)*136 + nt*16 + c] = f2b(v3);
        short4v pk;
        pk[0] = (short)f2b(v0); pk[1] = (short)f2b(v1);
        pk[2] = (short)f2b(v2); pk[3] = (short)f2b(v3);
        *(short4v*)(H2t + (nt*16+c)*16 + g*4) = pk;
      }
    }
    asm volatile("s_waitcnt lgkmcnt(0)" ::: "memory");

    // ---- LG: H2[16][128] @ [A4|Wg]^T -> logits (cols 0-7) + gates (8-15) ----
    f32x4 lg = (f32x4){0,0,0,0};
    {
      bf16x8 a2[4];
#pragma unroll
      for (int kb = 0; kb < 4; ++kb)
        a2[kb] = *(const bf16x8*)(H2 + c*136 + kb*32 + g*8);
#pragma unroll
      for (int kb = 0; kb < 4; ++kb)
        lg = MFMA(a2[kb], awf[kb], lg);
    }
    if (c < 8) {
#pragma unroll
      for (int i = 0; i < 4; ++i) {
        const int s = sbase + g*4 + i;
        float v = lg[i] + Lb[s*8 + c];
        if (s == r) v = -1e30f;
        lg[i] = v;
      }
    }

    // ---- online softmax (per head = col c<8; rows = senders) ----
    float t = fmaxf(fmaxf(lg[0], lg[1]), fmaxf(lg[2], lg[3]));
    t = fmaxf(t, __shfl_xor(t, 16));
    t = fmaxf(t, __shfl_xor(t, 32));
    const float mn = fmaxf(mrun, t);
    const float resc = __expf(mrun - mn);
    mrun = mn;
    float val[4];
    float wsum = 0.f;
#pragma unroll
    for (int i = 0; i < 4; ++i) { val[i] = __expf(lg[i] - mn); wsum += val[i]; }
    drun = fmaf(drun, resc, wsum);
    // route wgt to gate lanes; write P^T rows (0-7 wgt, 8-15 wgt*gate)
#pragma unroll
    for (int i = 0; i < 4; ++i) {
      const float oth = __shfl_xor(val[i], 8);
      const float fin = (c < 8) ? val[i] : oth * lg[i];
      wT[c*32 + g*4 + i] = f2b(fin);
    }
    if (l < 8) resp[l] = resc;
    asm volatile("s_waitcnt lgkmcnt(0)" ::: "memory");

    // ---- rescale accumulators by per-row resc ----
    float r4[4];
#pragma unroll
    for (int i = 0; i < 4; ++i) r4[i] = resp[(g*4 + i) & 7];
#pragma unroll
    for (int nt = 0; nt < 8; ++nt) {
#pragma unroll
      for (int i = 0; i < 4; ++i) { bh[nt][i] *= r4[i]; sna[nt][i] *= r4[i]; }
    }
#pragma unroll
    for (int q2 = 0; q2 < 2; ++q2) {
#pragma unroll
      for (int i = 0; i < 4; ++i) av2[q2][i] *= r4[i];
    }

    // ---- P-MFMAs: Bh += P@H2, sn += P@vn, avv += P@unit ----
    {
      const bf16x8 pa = *(const bf16x8*)(wT + c*32 + g*8);
#pragma unroll
      for (int nt = 0; nt < 8; ++nt)
        bh[nt] = MFMA(pa, *(const bf16x8*)(H2t + (nt*16+c)*16 + (g&1)*8), bh[nt]);
#pragma unroll
      for (int nt = 0; nt < 8; ++nt)
        sna[nt] = MFMA(pa, *(const bf16x8*)(vnT + (nt*16+c)*512 + sbase + g*8), sna[nt]);
#pragma unroll
      for (int q2 = 0; q2 < 2; ++q2)
        av2[q2] = MFMA(pa, *(const bf16x8*)(uC + (q2*16+c)*16 + (g&1)*8), av2[q2]);
    }
  }

  // ---- merge 4 waves ----
  drun += __shfl_xor(drun, 16);
  drun += __shfl_xor(drun, 32);
  __syncthreads();   // all waves done with per-wave tile buffers

  float* BhW  = (float*)Lds;              // [4][8][128]
  float* snW  = (float*)(Lds + 16384);    // [4][8][128]
  float* avvW = (float*)(Lds + 32768);    // [4][24]
  float* mW   = (float*)(Lds + 33152);    // [4][8]
  float* dW   = (float*)(Lds + 33280);    // [4][8]
  float* scl  = (float*)(Lds + 33408);    // [4][8]
  float* Dh   = (float*)(Lds + 33568);    // [8]
  float* Bm   = (float*)(Lds + 33600);    // [8][128]
  float* asB  = (float*)(Lds + 37696);    // [128]
  float* o1   = (float*)(Lds + 38208);    // [128]
  float* o2   = (float*)(Lds + 38720);    // [128]

  if (l < 32) {
#pragma unroll
    for (int nt = 0; nt < 8; ++nt) {
#pragma unroll
      for (int i = 0; i < 4; ++i) {
        const int row = g*4 + i;
        BhW[w*1024 + row*128 + nt*16 + c] = bh[nt][i];
        snW[w*1024 + row*128 + nt*16 + c] = sna[nt][i];
      }
    }
  } else {
#pragma unroll
    for (int q2 = 0; q2 < 2; ++q2) {
#pragma unroll
      for (int i = 0; i < 4; ++i) {
        const int row = g*4 + i;      // 8..15
        const int v = row - 8;
        const int col = q2*16 + c;
        if (col >= v*3 && col < v*3 + 3) avvW[w*24 + col] = av2[q2][i];
      }
    }
  }
  if (l < 8) { mW[w*8 + l] = mrun; dW[w*8 + l] = drun; }
  __syncthreads();

  if (tid < 8) {
    float M = -1e30f;
#pragma unroll
    for (int ww = 0; ww < 4; ++ww) M = fmaxf(M, mW[ww*8 + tid]);
    float D = 0.f;
#pragma unroll
    for (int ww = 0; ww < 4; ++ww) {
      const float sc = __expf(mW[ww*8 + tid] - M);
      scl[ww*8 + tid] = sc;
      D = fmaf(sc, dW[ww*8 + tid], D);
    }
    Dh[tid] = D;
  }
  __syncthreads();

  for (int idx = tid; idx < 1024; idx += 256) {
    const int h = idx >> 7;
    float acc = 0.f;
#pragma unroll
    for (int ww = 0; ww < 4; ++ww)
      acc = fmaf(scl[ww*8 + h], BhW[ww*1024 + idx], acc);
    Bm[idx] = acc;
  }
  if (tid >= 192 && tid < 216) {
    const int t = tid - 192, v = t / 3;
    float acc = 0.f;
#pragma unroll
    for (int ww = 0; ww < 4; ++ww)
      acc = fmaf(scl[ww*8 + v], avvW[ww*24 + t], acc);
    out[r*24 + t] = pos[r*24 + t] + 1.7320508076f * acc / Dh[v];
  }
  __syncthreads();

  if (tid < 128) {
    const int j = tid, hh = j >> 4;
    float sm = 0.f;
#pragma unroll
    for (int ww = 0; ww < 4; ++ww)
      sm = fmaf(scl[ww*8 + hh], snW[ww*1024 + hh*128 + j], sm);
    float ev = 0.f;
#pragma unroll 4
    for (int m = 0; m < 128; ++m)
      ev = fmaf(Bm[hh*128 + m], Wev[m*128 + j], ev);
    asB[j] = (sm + ev) / Dh[hh];
  }
  __syncthreads();
  if (tid < 128) {
    const int j = tid;
    float acc = bo0[j];
#pragma unroll 4
    for (int i = 0; i < 128; ++i) acc = fmaf(asB[i], Wo0[i*128 + j], acc);
    o1[j] = fsilu(acc);
  }
  __syncthreads();
  if (tid < 128) {
    const int j = tid;
    float acc = bo1[j];
#pragma unroll 4
    for (int i = 0; i < 128; ++i) acc = fmaf(o1[i], Wo1[i*128 + j], acc);
    o2[j] = fsilu(acc);
  }
  __syncthreads();
  if (tid < 128) {
    const int j = tid;
    float acc = bo2[j];
#pragma unroll 4
    for (int i = 0; i < 128; ++i) acc = fmaf(o2[i], Wo2[i*128 + j], acc);
    out[12288 + r*128 + j] = feat[r*128 + j] + acc;
  }
}

extern "C" void kernel_launch(void* const* d_in, const int* in_sizes, int n_in,
                              void* d_out, int out_size, void* d_ws, size_t ws_size,
                              hipStream_t stream)
{
  const float* pos  = (const float*)d_in[0];
  const float* feat = (const float*)d_in[1];
  const float* We0  = (const float*)d_in[2];
  const float* be0  = (const float*)d_in[3];
  const float* We1  = (const float*)d_in[4];
  const float* be1  = (const float*)d_in[5];
  const float* Wq   = (const float*)d_in[6];
  const float* Wk   = (const float*)d_in[7];
  const float* Wek  = (const float*)d_in[8];
  const float* Wv   = (const float*)d_in[9];
  const float* Wev  = (const float*)d_in[10];
  const float* Wg   = (const float*)d_in[11];
  const float* Wo0  = (const float*)d_in[12];
  const float* bo0  = (const float*)d_in[13];
  const float* Wo1  = (const float*)d_in[14];
  const float* bo1  = (const float*)d_in[15];
  const float* Wo2  = (const float*)d_in[16];
  const float* bo2  = (const float*)d_in[17];
  float* ws  = (float*)d_ws;
  float* out = (float*)d_out;

  hipLaunchKernelGGL(k_nodeprep, dim3(512), dim3(128), 0, stream,
                     feat, Wq, Wk, Wv, Wek, Wg, ws);
  hipLaunchKernelGGL(k_lbase, dim3(512), dim3(512), 0, stream, ws);
  hipLaunchKernelGGL(k_wprep, dim3(96), dim3(256), 0, stream, We0, We1, ws);
  hipLaunchKernelGGL(k_edge2, dim3(512), dim3(256), 0, stream,
                     pos, feat, be0, be1, Wev,
                     Wo0, bo0, Wo1, bo1, Wo2, bo2, ws, out);
}

// Round 3
// 195.078 us; speedup vs baseline: 2.3173x; 1.0775x over previous
//
#include <hip/hip_runtime.h>

// EnTransformerBlock, MFMA v3: occupancy-focused (3 blocks/CU), shorter chains.
// N=512, V=8, F=128, H=8, FH=16, B=8. Dense all-pairs edges.
//
// ws layout (float offsets):
//   kn    @ 0         f32 [512][128]
//   qn    @ 65536     f32 [512][128]
//   Lb    @ 131072    f32 [512][512][8]   (q.k per head, pre-divided by 4)
//   vnT   @ 2228224   bf16[128][512]      (feat@Wv transposed)
//   AWgT  @ 2260992   bf16[512][16][128]  (rows 0-7: Wek-folded-q /4; 8-15: Wg^T)
//   W0T   @ 2785280   bf16[128][64]       (We0 transposed)
//   W1T   @ 2789376   bf16[128][128]      (We1 transposed)

#define WS_KN   0
#define WS_QN   65536
#define WS_LB   131072
#define WS_VNT  2228224
#define WS_AWGT 2260992
#define WS_W0T  2785280
#define WS_W1T  2789376

typedef short bf16x8 __attribute__((ext_vector_type(8)));
typedef short short4v __attribute__((ext_vector_type(4)));
typedef float f32x4 __attribute__((ext_vector_type(4)));

static __device__ __forceinline__ unsigned short f2b(float x) {
  union { float f; unsigned u; } c; c.f = x;
  unsigned r = c.u + 0x7fffu + ((c.u >> 16) & 1u);
  return (unsigned short)(r >> 16);
}
static __device__ __forceinline__ float fsilu(float x) {
  return x / (1.f + __expf(-x));
}

__global__ __launch_bounds__(128) void k_nodeprep(
    const float* __restrict__ feat, const float* __restrict__ Wq,
    const float* __restrict__ Wk, const float* __restrict__ Wv,
    const float* __restrict__ Wek, const float* __restrict__ Wg,
    float* __restrict__ ws)
{
  const int r = blockIdx.x, j = threadIdx.x;
  __shared__ float fr[128];
  __shared__ float qL[128];
  fr[j] = feat[r*128 + j];
  __syncthreads();
  float aq = 0.f, ak = 0.f, av = 0.f;
#pragma unroll 4
  for (int i = 0; i < 128; ++i) {
    const float f = fr[i];
    aq = fmaf(f, Wq[i*128 + j], aq);
    ak = fmaf(f, Wk[i*128 + j], ak);
    av = fmaf(f, Wv[i*128 + j], av);
  }
  ws[WS_QN + r*128 + j] = aq;
  ws[WS_KN + r*128 + j] = ak;
  unsigned short* vnT = (unsigned short*)(ws + WS_VNT);
  vnT[j*512 + r] = f2b(av);
  qL[j] = aq;
  __syncthreads();
  unsigned short* AW = (unsigned short*)(ws + WS_AWGT) + r*2048;
  const float* wr = Wek + j*128;
#pragma unroll
  for (int h = 0; h < 8; ++h) {
    float acc = 0.f;
#pragma unroll
    for (int f = 0; f < 16; ++f)
      acc = fmaf(wr[16*h + f], qL[16*h + f], acc);
    AW[h*128 + j] = f2b(acc * 0.25f);
  }
#pragma unroll
  for (int v = 0; v < 8; ++v)
    AW[(8 + v)*128 + j] = f2b(Wg[j*8 + v]);
}

__global__ __launch_bounds__(512) void k_lbase(float* __restrict__ ws)
{
  const int r = blockIdx.x, s = threadIdx.x;
  __shared__ float qL[128];
  if (s < 128) qL[s] = ws[WS_QN + r*128 + s];
  __syncthreads();
  const float* knr = ws + WS_KN + s*128;
  float* Lb = ws + WS_LB + (r*512 + s)*8;
#pragma unroll
  for (int h = 0; h < 8; ++h) {
    float acc = 0.f;
#pragma unroll
    for (int f = 0; f < 16; ++f)
      acc = fmaf(knr[16*h + f], qL[16*h + f], acc);
    Lb[h] = acc * 0.25f;
  }
}

__global__ __launch_bounds__(256) void k_wprep(
    const float* __restrict__ We0, const float* __restrict__ We1,
    float* __restrict__ ws)
{
  const int i = blockIdx.x*256 + threadIdx.x;
  unsigned short* W0T = (unsigned short*)(ws + WS_W0T);
  unsigned short* W1T = (unsigned short*)(ws + WS_W1T);
  if (i < 8192) {
    const int n = i >> 6, k = i & 63;
    W0T[n*64 + k] = f2b(We0[k*128 + n]);
  } else if (i < 24576) {
    const int t = i - 8192, n = t >> 7, k = t & 127;
    W1T[n*128 + k] = f2b(We1[k*128 + n]);
  }
}

// per-wave LDS (bytes from wave base, WSTR=13120):
//   H1   @ 0      bf16[16][128]  XOR-swizzled ((row&7)<<3 on short col)
//   H2r  @ 4096   bf16[16][128]  XOR-swizzled
//   H2t  @ 8192   bf16[128][16]
//   uC   @ 12288  bf16[24][16]
//   resp @ 13056  f32[8]
// merge phase aliases from Lds base 0 after __syncthreads (max 39232 B).
#define WSTR 13120

#define MFMA(a,b,c) __builtin_amdgcn_mfma_f32_16x16x32_bf16((a),(b),(c),0,0,0)

__global__ __launch_bounds__(256, 4) void k_edge3(
    const float* __restrict__ pos, const float* __restrict__ feat,
    const float* __restrict__ be0, const float* __restrict__ be1,
    const float* __restrict__ Wev,
    const float* __restrict__ Wo0, const float* __restrict__ bo0,
    const float* __restrict__ Wo1, const float* __restrict__ bo1,
    const float* __restrict__ Wo2, const float* __restrict__ bo2,
    const float* __restrict__ ws, float* __restrict__ out)
{
  __shared__ __align__(16) char Lds[53248];
  const int tid = threadIdx.x;
  const int w = tid >> 6, l = tid & 63;
  const int r = blockIdx.x;
  const int c = l & 15, g = l >> 4;

  char* Wb = Lds + w*WSTR;
  unsigned short* H1  = (unsigned short*)(Wb);
  unsigned short* H2r = (unsigned short*)(Wb + 4096);
  unsigned short* H2t = (unsigned short*)(Wb + 8192);
  unsigned short* uC  = (unsigned short*)(Wb + 12288);
  float* resp = (float*)(Wb + 13056);

  const unsigned short* vnT = (const unsigned short*)(ws + WS_VNT);
  const unsigned short* AWg = (const unsigned short*)(ws + WS_AWGT) + r*2048;
  const unsigned short* W0T = (const unsigned short*)(ws + WS_W0T);
  const unsigned short* W1T = (const unsigned short*)(ws + WS_W1T);
  const float* Lb = ws + WS_LB + r*4096;

  // receiver positions for this lane's two vectors (v=g, v=g+4)
  const float pr0x = pos[r*24 + g*3 + 0];
  const float pr0y = pos[r*24 + g*3 + 1];
  const float pr0z = pos[r*24 + g*3 + 2];
  const float pr1x = pos[r*24 + (g+4)*3 + 0];
  const float pr1y = pos[r*24 + (g+4)*3 + 1];
  const float pr1z = pos[r*24 + (g+4)*3 + 2];

  f32x4 bh[8], sna[8], av2[2];
#pragma unroll
  for (int nt = 0; nt < 8; ++nt) { bh[nt] = (f32x4){0,0,0,0}; sna[nt] = (f32x4){0,0,0,0}; }
  av2[0] = (f32x4){0,0,0,0}; av2[1] = (f32x4){0,0,0,0};
  float mrun = -1e30f, drun = 0.f;

  for (int tile = w; tile < 32; tile += 4) {
    const int sbase = tile << 4;
    const int s = sbase + c;

    // ---- geometry, directly in L0 A-frag layout (lane = sender c, v=g / g+4) ----
    bf16x8 af0, af1;
    {
      const float dx0 = pos[s*24 + g*3 + 0] - pr0x;
      const float dy0 = pos[s*24 + g*3 + 1] - pr0y;
      const float dz0 = pos[s*24 + g*3 + 2] - pr0z;
      const float l20 = fmaf(dx0,dx0, fmaf(dy0,dy0, fmaf(dz0,dz0, 1e-20f)));
      const float inv0 = rsqrtf(l20);
      const float len0 = l20 * inv0;
      uC[(g*3+0)*16 + c] = f2b(dx0*inv0);
      uC[(g*3+1)*16 + c] = f2b(dy0*inv0);
      uC[(g*3+2)*16 + c] = f2b(dz0*inv0);
      const float y0 = 2.f - len0*0.2f;
      const float env0 = (y0 > 0.f) ? 1.9784655648f * __expf(-1.f/y0) : 0.f;
      const float coef0 = 0.4472135955f * env0 * inv0;
      const float arg0 = len0 * 0.31415926535f;
      float s1 = __sinf(arg0), c1 = __cosf(arg0);
      float twc = 2.f*c1, sp = 0.f, sc = s1;
#pragma unroll
      for (int b = 0; b < 8; ++b) {
        af0[b] = (short)f2b(coef0*sc);
        const float nx = fmaf(twc, sc, -sp);
        sp = sc; sc = nx;
      }
      const float dx1 = pos[s*24 + (g+4)*3 + 0] - pr1x;
      const float dy1 = pos[s*24 + (g+4)*3 + 1] - pr1y;
      const float dz1 = pos[s*24 + (g+4)*3 + 2] - pr1z;
      const float l21 = fmaf(dx1,dx1, fmaf(dy1,dy1, fmaf(dz1,dz1, 1e-20f)));
      const float inv1 = rsqrtf(l21);
      const float len1 = l21 * inv1;
      uC[((g+4)*3+0)*16 + c] = f2b(dx1*inv1);
      uC[((g+4)*3+1)*16 + c] = f2b(dy1*inv1);
      uC[((g+4)*3+2)*16 + c] = f2b(dz1*inv1);
      const float y1 = 2.f - len1*0.2f;
      const float env1 = (y1 > 0.f) ? 1.9784655648f * __expf(-1.f/y1) : 0.f;
      const float coef1 = 0.4472135955f * env1 * inv1;
      const float arg1 = len1 * 0.31415926535f;
      s1 = __sinf(arg1); c1 = __cosf(arg1);
      twc = 2.f*c1; sp = 0.f; sc = s1;
#pragma unroll
      for (int b = 0; b < 8; ++b) {
        af1[b] = (short)f2b(coef1*sc);
        const float nx = fmaf(twc, sc, -sp);
        sp = sc; sc = nx;
      }
    }

    // ---- L0: Es[16][64] @ We0 -> H1 (swizzled) ----
#pragma unroll
    for (int nt = 0; nt < 8; ++nt) {
      f32x4 acc = (f32x4){0,0,0,0};
      acc = MFMA(af0, *(const bf16x8*)(W0T + (nt*16+c)*64 + g*8), acc);
      acc = MFMA(af1, *(const bf16x8*)(W0T + (nt*16+c)*64 + 32 + g*8), acc);
      const float b0 = be0[nt*16 + c];
#pragma unroll
      for (int i = 0; i < 4; ++i) {
        const int row = g*4 + i;
        H1[row*128 + ((nt*16+c) ^ ((row&7)<<3))] = f2b(fsilu(acc[i] + b0));
      }
    }

    // ---- L1: H1[16][128] @ We1 -> H2r (swizzled) + H2t ----
    {
      bf16x8 a1[4];
#pragma unroll
      for (int kb = 0; kb < 4; ++kb)
        a1[kb] = *(const bf16x8*)(H1 + c*128 + ((kb*32 + g*8) ^ ((c&7)<<3)));
#pragma unroll
      for (int nt = 0; nt < 8; ++nt) {
        f32x4 acc = (f32x4){0,0,0,0};
#pragma unroll
        for (int kb = 0; kb < 4; ++kb)
          acc = MFMA(a1[kb], *(const bf16x8*)(W1T + (nt*16+c)*128 + kb*32 + g*8), acc);
        const float b1 = be1[nt*16 + c];
        short4v pk;
#pragma unroll
        for (int i = 0; i < 4; ++i) {
          const int row = g*4 + i;
          const float v = fsilu(acc[i] + b1);
          const unsigned short bv = f2b(v);
          H2r[row*128 + ((nt*16+c) ^ ((row&7)<<3))] = bv;
          pk[i] = (short)bv;
        }
        *(short4v*)(H2t + (nt*16+c)*16 + g*4) = pk;
      }
    }

    // ---- LG: H2[16][128] @ [A4|Wg]^T -> logits (cols 0-7) + gates (8-15) ----
    f32x4 lg = (f32x4){0,0,0,0};
    {
#pragma unroll
      for (int kb = 0; kb < 4; ++kb) {
        const bf16x8 a2 = *(const bf16x8*)(H2r + c*128 + ((kb*32 + g*8) ^ ((c&7)<<3)));
        lg = MFMA(a2, *(const bf16x8*)(AWg + c*128 + kb*32 + g*8), lg);
      }
    }
    if (c < 8) {
#pragma unroll
      for (int i = 0; i < 4; ++i) {
        const int ss = sbase + g*4 + i;
        float v = lg[i] + Lb[ss*8 + c];
        if (ss == r) v = -1e30f;
        lg[i] = v;
      }
    }

    // ---- online softmax (head = col c<8, senders = rows) ----
    float t = fmaxf(fmaxf(lg[0], lg[1]), fmaxf(lg[2], lg[3]));
    t = fmaxf(t, __shfl_xor(t, 16));
    t = fmaxf(t, __shfl_xor(t, 32));
    const float mn = fmaxf(mrun, t);
    const float resc = __expf(mrun - mn);
    mrun = mn;
    float val[4], fin[4];
    float wsum = 0.f;
#pragma unroll
    for (int i = 0; i < 4; ++i) { val[i] = __expf(lg[i] - mn); wsum += val[i]; }
    drun = fmaf(drun, resc, wsum);
#pragma unroll
    for (int i = 0; i < 4; ++i) {
      const float oth = __shfl_xor(val[i], 8);
      fin[i] = (c < 8) ? val[i] : oth * lg[i];
    }
    if (l < 8) resp[l] = resc;

    // ---- build P A-frag in-register via shfl (k = sender; g>=2 -> zero) ----
    bf16x8 pa;
    {
      const int srcA = 32*g + c, srcB = srcA + 16;
      const bool act = (g < 2);
#pragma unroll
      for (int j = 0; j < 8; ++j) {
        const float v = __shfl(fin[j & 3], (j < 4) ? srcA : srcB);
        pa[j] = act ? (short)f2b(v) : (short)0;
      }
    }

    // ---- rescale accumulators by per-head resc ----
    float r4[4];
#pragma unroll
    for (int i = 0; i < 4; ++i) r4[i] = resp[(g*4 + i) & 7];
#pragma unroll
    for (int nt = 0; nt < 8; ++nt) {
#pragma unroll
      for (int i = 0; i < 4; ++i) { bh[nt][i] *= r4[i]; sna[nt][i] *= r4[i]; }
    }
#pragma unroll
    for (int q2 = 0; q2 < 2; ++q2) {
#pragma unroll
      for (int i = 0; i < 4; ++i) av2[q2][i] *= r4[i];
    }

    // ---- P-MFMAs: bh += P@H2, sna += P@vn, av2 += P@unit ----
#pragma unroll
    for (int nt = 0; nt < 8; ++nt)
      bh[nt] = MFMA(pa, *(const bf16x8*)(H2t + (nt*16+c)*16 + (g&1)*8), bh[nt]);
#pragma unroll
    for (int nt = 0; nt < 8; ++nt)
      sna[nt] = MFMA(pa, *(const bf16x8*)(vnT + (nt*16+c)*512 + sbase + (g&1)*8), sna[nt]);
#pragma unroll
    for (int q2 = 0; q2 < 2; ++q2)
      av2[q2] = MFMA(pa, *(const bf16x8*)(uC + (q2*16+c)*16 + (g&1)*8), av2[q2]);
  }

  // ---- merge 4 waves ----
  drun += __shfl_xor(drun, 16);
  drun += __shfl_xor(drun, 32);
  __syncthreads();

  float* BhW  = (float*)Lds;              // [4][8][128]
  float* snW  = (float*)(Lds + 16384);    // [4][8][128]
  float* avvW = (float*)(Lds + 32768);    // [4][24]
  float* mW   = (float*)(Lds + 33152);    // [4][8]
  float* dW   = (float*)(Lds + 33280);    // [4][8]
  float* scl  = (float*)(Lds + 33408);    // [4][8]
  float* Dh   = (float*)(Lds + 33568);    // [8]
  float* Bm   = (float*)(Lds + 33600);    // [8][128]
  float* asB  = (float*)(Lds + 37696);    // [128]
  float* o1   = (float*)(Lds + 38208);    // [128]
  float* o2   = (float*)(Lds + 38720);    // [128]

  if (l < 32) {
#pragma unroll
    for (int nt = 0; nt < 8; ++nt) {
#pragma unroll
      for (int i = 0; i < 4; ++i) {
        const int row = g*4 + i;
        BhW[w*1024 + row*128 + nt*16 + c] = bh[nt][i];
        snW[w*1024 + row*128 + nt*16 + c] = sna[nt][i];
      }
    }
  } else {
#pragma unroll
    for (int q2 = 0; q2 < 2; ++q2) {
#pragma unroll
      for (int i = 0; i < 4; ++i) {
        const int row = g*4 + i;      // 8..15
        const int v = row - 8;
        const int col = q2*16 + c;
        if (col >= v*3 && col < v*3 + 3) avvW[w*24 + col] = av2[q2][i];
      }
    }
  }
  if (l < 8) { mW[w*8 + l] = mrun; dW[w*8 + l] = drun; }
  __syncthreads();

  if (tid < 8) {
    float M = -1e30f;
#pragma unroll
    for (int ww = 0; ww < 4; ++ww) M = fmaxf(M, mW[ww*8 + tid]);
    float D = 0.f;
#pragma unroll
    for (int ww = 0; ww < 4; ++ww) {
      const float sc = __expf(mW[ww*8 + tid] - M);
      scl[ww*8 + tid] = sc;
      D = fmaf(sc, dW[ww*8 + tid], D);
    }
    Dh[tid] = D;
  }
  __syncthreads();

  for (int idx = tid; idx < 1024; idx += 256) {
    const int h = idx >> 7;
    float acc = 0.f;
#pragma unroll
    for (int ww = 0; ww < 4; ++ww)
      acc = fmaf(scl[ww*8 + h], BhW[ww*1024 + idx], acc);
    Bm[idx] = acc;
  }
  if (tid >= 192 && tid < 216) {
    const int t = tid - 192, v = t / 3;
    float acc = 0.f;
#pragma unroll
    for (int ww = 0; ww < 4; ++ww)
      acc = fmaf(scl[ww*8 + v], avvW[ww*24 + t], acc);
    out[r*24 + t] = pos[r*24 + t] + 1.7320508076f * acc / Dh[v];
  }
  __syncthreads();

  if (tid < 128) {
    const int j = tid, hh = j >> 4;
    float sm = 0.f;
#pragma unroll
    for (int ww = 0; ww < 4; ++ww)
      sm = fmaf(scl[ww*8 + hh], snW[ww*1024 + hh*128 + j], sm);
    float ev = 0.f;
#pragma unroll 4
    for (int m = 0; m < 128; ++m)
      ev = fmaf(Bm[hh*128 + m], Wev[m*128 + j], ev);
    asB[j] = (sm + ev) / Dh[hh];
  }
  __syncthreads();
  if (tid < 128) {
    const int j = tid;
    float acc = bo0[j];
#pragma unroll 4
    for (int i = 0; i < 128; ++i) acc = fmaf(asB[i], Wo0[i*128 + j], acc);
    o1[j] = fsilu(acc);
  }
  __syncthreads();
  if (tid < 128) {
    const int j = tid;
    float acc = bo1[j];
#pragma unroll 4
    for (int i = 0; i < 128; ++i) acc = fmaf(o1[i], Wo1[i*128 + j], acc);
    o2[j] = fsilu(acc);
  }
  __syncthreads();
  if (tid < 128) {
    const int j = tid;
    float acc = bo2[j];
#pragma unroll 4
    for (int i = 0; i < 128; ++i) acc = fmaf(o2[i], Wo2[i*128 + j], acc);
    out[12288 + r*128 + j] = feat[r*128 + j] + acc;
  }
}

extern "C" void kernel_launch(void* const* d_in, const int* in_sizes, int n_in,
                              void* d_out, int out_size, void* d_ws, size_t ws_size,
                              hipStream_t stream)
{
  const float* pos  = (const float*)d_in[0];
  const float* feat = (const float*)d_in[1];
  const float* We0  = (const float*)d_in[2];
  const float* be0  = (const float*)d_in[3];
  const float* We1  = (const float*)d_in[4];
  const float* be1  = (const float*)d_in[5];
  const float* Wq   = (const float*)d_in[6];
  const float* Wk   = (const float*)d_in[7];
  const float* Wek  = (const float*)d_in[8];
  const float* Wv   = (const float*)d_in[9];
  const float* Wev  = (const float*)d_in[10];
  const float* Wg   = (const float*)d_in[11];
  const float* Wo0  = (const float*)d_in[12];
  const float* bo0  = (const float*)d_in[13];
  const float* Wo1  = (const float*)d_in[14];
  const float* bo1  = (const float*)d_in[15];
  const float* Wo2  = (const float*)d_in[16];
  const float* bo2  = (const float*)d_in[17];
  float* ws  = (float*)d_ws;
  float* out = (float*)d_out;

  hipLaunchKernelGGL(k_nodeprep, dim3(512), dim3(128), 0, stream,
                     feat, Wq, Wk, Wv, Wek, Wg, ws);
  hipLaunchKernelGGL(k_lbase, dim3(512), dim3(512), 0, stream, ws);
  hipLaunchKernelGGL(k_wprep, dim3(96), dim3(256), 0, stream, We0, We1, ws);
  hipLaunchKernelGGL(k_edge3, dim3(512), dim3(256), 0, stream,
                     pos, feat, be0, be1, Wev,
                     Wo0, bo0, Wo1, bo1, Wo2, bo2, ws, out);
}

// Round 4
// 150.534 us; speedup vs baseline: 3.0031x; 1.2959x over previous
//
#include <hip/hip_runtime.h>

// EnTransformerBlock, MFMA v4: cooperative 8-wave blocks, col-partitioned.
// N=512, V=8, F=128, H=8, FH=16, B=8. Dense all-pairs edges.
//
// ws layout (float offsets):
//   kn    @ 0         f32 [512][128]
//   qn    @ 65536     f32 [512][128]
//   Lb    @ 131072    f32 [512][512][8]   (q.k per head, pre-divided by 4)
//   vnT   @ 2228224   bf16[128][512]      (feat@Wv transposed)
//   AWgT  @ 2260992   bf16[512][16][128]  (rows 0-7: Wek-folded-q /4; 8-15: Wg^T)
//   W0T   @ 2785280   bf16[128][64]       (We0 transposed)
//   W1T   @ 2789376   bf16[128][128]      (We1 transposed)

#define WS_KN   0
#define WS_QN   65536
#define WS_LB   131072
#define WS_VNT  2228224
#define WS_AWGT 2260992
#define WS_W0T  2785280
#define WS_W1T  2789376

typedef short bf16x8 __attribute__((ext_vector_type(8)));
typedef short short4v __attribute__((ext_vector_type(4)));
typedef float f32x4 __attribute__((ext_vector_type(4)));

static __device__ __forceinline__ unsigned short f2b(float x) {
  union { float f; unsigned u; } c; c.f = x;
  unsigned r = c.u + 0x7fffu + ((c.u >> 16) & 1u);
  return (unsigned short)(r >> 16);
}
static __device__ __forceinline__ float fsilu(float x) {
  return x / (1.f + __expf(-x));
}

__global__ __launch_bounds__(128) void k_nodeprep(
    const float* __restrict__ feat, const float* __restrict__ Wq,
    const float* __restrict__ Wk, const float* __restrict__ Wv,
    const float* __restrict__ Wek, const float* __restrict__ Wg,
    float* __restrict__ ws)
{
  const int r = blockIdx.x, j = threadIdx.x;
  __shared__ float fr[128];
  __shared__ float qL[128];
  fr[j] = feat[r*128 + j];
  __syncthreads();
  float aq = 0.f, ak = 0.f, av = 0.f;
#pragma unroll 4
  for (int i = 0; i < 128; ++i) {
    const float f = fr[i];
    aq = fmaf(f, Wq[i*128 + j], aq);
    ak = fmaf(f, Wk[i*128 + j], ak);
    av = fmaf(f, Wv[i*128 + j], av);
  }
  ws[WS_QN + r*128 + j] = aq;
  ws[WS_KN + r*128 + j] = ak;
  unsigned short* vnT = (unsigned short*)(ws + WS_VNT);
  vnT[j*512 + r] = f2b(av);
  qL[j] = aq;
  __syncthreads();
  unsigned short* AW = (unsigned short*)(ws + WS_AWGT) + r*2048;
  const float* wr = Wek + j*128;
#pragma unroll
  for (int h = 0; h < 8; ++h) {
    float acc = 0.f;
#pragma unroll
    for (int f = 0; f < 16; ++f)
      acc = fmaf(wr[16*h + f], qL[16*h + f], acc);
    AW[h*128 + j] = f2b(acc * 0.25f);
  }
#pragma unroll
  for (int v = 0; v < 8; ++v)
    AW[(8 + v)*128 + j] = f2b(Wg[j*8 + v]);
}

__global__ __launch_bounds__(512) void k_lbase(float* __restrict__ ws)
{
  const int r = blockIdx.x, s = threadIdx.x;
  __shared__ float qL[128];
  if (s < 128) qL[s] = ws[WS_QN + r*128 + s];
  __syncthreads();
  const float* knr = ws + s*128;
  float* Lb = ws + WS_LB + (r*512 + s)*8;
#pragma unroll
  for (int h = 0; h < 8; ++h) {
    float acc = 0.f;
#pragma unroll
    for (int f = 0; f < 16; ++f)
      acc = fmaf(knr[16*h + f], qL[16*h + f], acc);
    Lb[h] = acc * 0.25f;
  }
}

__global__ __launch_bounds__(256) void k_wprep(
    const float* __restrict__ We0, const float* __restrict__ We1,
    float* __restrict__ ws)
{
  const int i = blockIdx.x*256 + threadIdx.x;
  unsigned short* W0T = (unsigned short*)(ws + WS_W0T);
  unsigned short* W1T = (unsigned short*)(ws + WS_W1T);
  if (i < 8192) {
    const int n = i >> 6, k = i & 63;
    W0T[n*64 + k] = f2b(We0[k*128 + n]);
  } else if (i < 24576) {
    const int t = i - 8192, n = t >> 7, k = t & 127;
    W1T[n*128 + k] = f2b(We1[k*128 + n]);
  }
}

// Block LDS map (bytes):
//   Es   @ 0      bf16[64][64]   8192   (8-blk XOR swizzle by row&7)
//   H1   @ 8192   bf16[64][128] 16384   (16-blk XOR swizzle by row&15)
//   H2r  @ 24576  bf16[64][128] 16384   (16-blk swizzle)
//   H2t  @ 40960  bf16[128][64] 16384   (8-blk swizzle)  rows=feat col, cols=sender
//   uCt  @ 57344  bf16[32][64]   4096   (8-blk swizzle)  rows 24-31 zero
//   Pb   @ 61440  bf16[16][64]   2048   (8-blk swizzle)  rows=channel
//   AWgL @ 63488  bf16[16][128]  4096   (16-blk swizzle)
//   LbL  @ 67584  f32 [64][8]    2048
//   mxL  @ 69632  f32 [4][8]      128
//   wsL  @ 69760  f32 [4][8]      128
//   DhL  @ 69888  f32 [8]          32
// merge aliases (post-loop): BhL@0 [8][128]f32, snL@4096 [8][128]f32,
//   avL@8192 [8][24]f32, asB@8960 [128]f32, o1@9472, o2@9984

#define MFMA(a,b,c) __builtin_amdgcn_mfma_f32_16x16x32_bf16((a),(b),(c),0,0,0)

__global__ __launch_bounds__(512, 4) void k_edge4(
    const float* __restrict__ pos, const float* __restrict__ feat,
    const float* __restrict__ be0, const float* __restrict__ be1,
    const float* __restrict__ Wev,
    const float* __restrict__ Wo0, const float* __restrict__ bo0,
    const float* __restrict__ Wo1, const float* __restrict__ bo1,
    const float* __restrict__ Wo2, const float* __restrict__ bo2,
    const float* __restrict__ ws, float* __restrict__ out)
{
  __shared__ __align__(16) char Lds[70016];
  const int tid = threadIdx.x;
  const int nw = tid >> 6, l = tid & 63;
  const int r = blockIdx.x;
  const int c = l & 15, g = l >> 4;

  unsigned short* Es   = (unsigned short*)(Lds + 0);
  unsigned short* H1   = (unsigned short*)(Lds + 8192);
  unsigned short* H2r  = (unsigned short*)(Lds + 24576);
  unsigned short* H2t  = (unsigned short*)(Lds + 40960);
  unsigned short* uCt  = (unsigned short*)(Lds + 57344);
  unsigned short* Pb   = (unsigned short*)(Lds + 61440);
  unsigned short* AWgL = (unsigned short*)(Lds + 63488);
  float* LbL = (float*)(Lds + 67584);
  float* mxL = (float*)(Lds + 69632);
  float* wsL = (float*)(Lds + 69760);
  float* DhL = (float*)(Lds + 69888);

  const unsigned short* vnT = (const unsigned short*)(ws + WS_VNT);
  const unsigned short* W0T = (const unsigned short*)(ws + WS_W0T);
  const unsigned short* W1T = (const unsigned short*)(ws + WS_W1T);
  const float* LbG = ws + WS_LB + r*4096;

  // stage AWgL (swizzled) + zero uCt pad rows (24-31)
  {
    const unsigned short* AWgG = (const unsigned short*)(ws + WS_AWGT) + r*2048;
    const int ch = tid >> 5, cs = (tid & 31)*4;
    *(short4v*)(AWgL + ch*128 + (((cs>>3) ^ ch)<<3) + (cs&7)) =
        *(const short4v*)(AWgG + ch*128 + cs);
    uCt[24*64 + tid] = 0;
  }

  // geometry identity: one edge-vector per thread
  const int sl = tid >> 3, v = tid & 7;
  const float prx = pos[r*24 + v*3 + 0];
  const float pry = pos[r*24 + v*3 + 1];
  const float prz = pos[r*24 + v*3 + 2];

  // wave column ownership
  const int ncol = nw*16 + c;
  const float be0v = be0[ncol], be1v = be1[ncol];
  const bf16x8 w0f0 = *(const bf16x8*)(W0T + ncol*64 + g*8);
  const bf16x8 w0f1 = *(const bf16x8*)(W0T + ncol*64 + 32 + g*8);

  f32x4 bh = {0,0,0,0}, sna = {0,0,0,0}, av = {0,0,0,0};
  float mrun[4] = {-1e30f,-1e30f,-1e30f,-1e30f};
  float drun[4] = {0.f,0.f,0.f,0.f};
  float mrun_c = -1e30f;
  const int hb = (g & 1)*4;

  __syncthreads();

  for (int it = 0; it < 8; ++it) {
    const int sbase = it << 6;
    // ---- prefetch (consumed much later) ----
    const float lbv = LbG[sbase*8 + tid];
    const bf16x8 vnf0 = *(const bf16x8*)(vnT + ncol*512 + sbase + g*8);
    const bf16x8 vnf1 = *(const bf16x8*)(vnT + ncol*512 + sbase + 32 + g*8);
    bf16x8 w1f[4];
#pragma unroll
    for (int kb = 0; kb < 4; ++kb)
      w1f[kb] = *(const bf16x8*)(W1T + ncol*128 + kb*32 + g*8);

    // ---- geometry ----
    {
      const int sg = sbase + sl;
      const float dx = pos[sg*24 + v*3 + 0] - prx;
      const float dy = pos[sg*24 + v*3 + 1] - pry;
      const float dz = pos[sg*24 + v*3 + 2] - prz;
      const float l2 = fmaf(dx,dx, fmaf(dy,dy, fmaf(dz,dz, 1e-20f)));
      const float inv = rsqrtf(l2);
      const float len = l2 * inv;
      uCt[(v*3+0)*64 + (((sl>>3) ^ ((v*3+0)&7))<<3) + (sl&7)] = f2b(dx*inv);
      uCt[(v*3+1)*64 + (((sl>>3) ^ ((v*3+1)&7))<<3) + (sl&7)] = f2b(dy*inv);
      uCt[(v*3+2)*64 + (((sl>>3) ^ ((v*3+2)&7))<<3) + (sl&7)] = f2b(dz*inv);
      const float yy = 2.f - len*0.2f;
      const float env = (yy > 0.f) ? 1.9784655648f * __expf(-1.f/yy) : 0.f;
      const float coef = 0.4472135955f * env * inv;
      const float arg = len * 0.31415926535f;
      const float s1 = __sinf(arg), c1 = __cosf(arg);
      const float twc = 2.f*c1;
      float sp = 0.f, sc = s1;
      bf16x8 ev;
#pragma unroll
      for (int b = 0; b < 8; ++b) {
        ev[b] = (short)f2b(coef*sc);
        const float nx = fmaf(twc, sc, -sp);
        sp = sc; sc = nx;
      }
      *(bf16x8*)(Es + sl*64 + ((v ^ (sl&7))<<3)) = ev;
    }
    __syncthreads();  // A: Es/uCt ready

    // ---- L0: Es[64][64] @ We0 -> H1 ----
    {
      f32x4 a0[4];
#pragma unroll
      for (int m = 0; m < 4; ++m) {
        const int ra = m*16 + c;
        const bf16x8 e0 = *(const bf16x8*)(Es + ra*64 + (((g  ) ^ (ra&7))<<3));
        const bf16x8 e1 = *(const bf16x8*)(Es + ra*64 + (((4+g) ^ (ra&7))<<3));
        f32x4 acc = {0,0,0,0};
        acc = MFMA(e0, w0f0, acc);
        acc = MFMA(e1, w0f1, acc);
        a0[m] = acc;
      }
#pragma unroll
      for (int m = 0; m < 4; ++m)
#pragma unroll
        for (int i = 0; i < 4; ++i) {
          const int row = m*16 + g*4 + i;
          H1[row*128 + ((((ncol>>3)) ^ (row&15))<<3) + (c&7)] =
              f2b(fsilu(a0[m][i] + be0v));
        }
    }
    LbL[tid] = lbv;
    __syncthreads();  // B: H1 ready

    // ---- L1: H1[64][128] @ We1 -> H2r + H2t ----
    {
      f32x4 a1[4];
#pragma unroll
      for (int m = 0; m < 4; ++m) {
        const int ra = m*16 + c;
        f32x4 acc = {0,0,0,0};
#pragma unroll
        for (int kb = 0; kb < 4; ++kb) {
          const bf16x8 af = *(const bf16x8*)(H1 + ra*128 + (((kb*4+g) ^ (ra&15))<<3));
          acc = MFMA(af, w1f[kb], acc);
        }
        a1[m] = acc;
      }
#pragma unroll
      for (int m = 0; m < 4; ++m) {
        short4v pk;
#pragma unroll
        for (int i = 0; i < 4; ++i) {
          const int row = m*16 + g*4 + i;
          const float vv = fsilu(a1[m][i] + be1v);
          const unsigned short bv = f2b(vv);
          H2r[row*128 + (((ncol>>3) ^ (row&15))<<3) + (c&7)] = bv;
          pk[i] = (short)bv;
        }
        *(short4v*)(H2t + ncol*64 + ((((m<<1)+(g>>1)) ^ (ncol&7))<<3) + ((g&1)<<2)) = pk;
      }
    }
    __syncthreads();  // C: H2r/H2t ready

    // ---- LG + tile submax (waves 0-3, 16 senders each) ----
    float lgv[4];
    if (nw < 4) {
      const int ra = nw*16 + c;
      f32x4 acc = {0,0,0,0};
#pragma unroll
      for (int kb = 0; kb < 4; ++kb) {
        const bf16x8 af = *(const bf16x8*)(H2r + ra*128 + (((kb*4+g) ^ (ra&15))<<3));
        const bf16x8 bf = *(const bf16x8*)(AWgL + c*128 + (((kb*4+g) ^ c)<<3));
        acc = MFMA(af, bf, acc);
      }
#pragma unroll
      for (int i = 0; i < 4; ++i) lgv[i] = acc[i];
      if (c < 8) {
#pragma unroll
        for (int i = 0; i < 4; ++i) {
          const int srow = nw*16 + g*4 + i;
          lgv[i] += LbL[srow*8 + c];
          if (sbase + srow == r) lgv[i] = -1e30f;
        }
      }
      float t = fmaxf(fmaxf(lgv[0], lgv[1]), fmaxf(lgv[2], lgv[3]));
      t = fmaxf(t, __shfl_xor(t, 16));
      t = fmaxf(t, __shfl_xor(t, 32));
      if (g == 0 && c < 8) mxL[nw*8 + c] = t;
    }
    __syncthreads();  // s1: mxL ready

    // ---- all waves: per-row-head state ----
    float rsc[4];
#pragma unroll
    for (int i = 0; i < 4; ++i) {
      const int h = hb + i;
      const float tm = fmaxf(fmaxf(mxL[h], mxL[8+h]), fmaxf(mxL[16+h], mxL[24+h]));
      const float mnew = fmaxf(mrun[i], tm);
      rsc[i] = __expf(mrun[i] - mnew);
      mrun[i] = mnew;
    }
    // ---- owners: P values + wsum ----
    if (nw < 4) {
      const int hc = c & 7;
      const float tmc = fmaxf(fmaxf(mxL[hc], mxL[8+hc]), fmaxf(mxL[16+hc], mxL[24+hc]));
      mrun_c = fmaxf(mrun_c, tmc);
      float val[4], wsp = 0.f;
#pragma unroll
      for (int i = 0; i < 4; ++i) { val[i] = __expf(lgv[i] - mrun_c); wsp += val[i]; }
      wsp += __shfl_xor(wsp, 16);
      wsp += __shfl_xor(wsp, 32);
      if (g == 0 && c < 8) wsL[nw*8 + c] = wsp;
      short4v pkp;
#pragma unroll
      for (int i = 0; i < 4; ++i) {
        const float oth = __shfl_xor(val[i], 8);
        const float fin = (c < 8) ? val[i] : oth * lgv[i];
        pkp[i] = (short)f2b(fin);
      }
      *(short4v*)(Pb + c*64 + ((((nw<<1)+(g>>1)) ^ (c&7))<<3) + ((g&1)<<2)) = pkp;
    }
    __syncthreads();  // s2: Pb/wsL ready

    // ---- all waves: drun, rescale, P-MFMAs ----
#pragma unroll
    for (int i = 0; i < 4; ++i) {
      const int h = hb + i;
      drun[i] = drun[i]*rsc[i] + (wsL[h] + wsL[8+h] + wsL[16+h] + wsL[24+h]);
      bh[i] *= rsc[i]; sna[i] *= rsc[i]; av[i] *= rsc[i];
    }
    const bf16x8 pa0 = *(const bf16x8*)(Pb + c*64 + (((g  ) ^ (c&7))<<3));
    const bf16x8 pa1 = *(const bf16x8*)(Pb + c*64 + (((4+g) ^ (c&7))<<3));
    bh = MFMA(pa0, *(const bf16x8*)(H2t + ncol*64 + (((g  ) ^ (ncol&7))<<3)), bh);
    bh = MFMA(pa1, *(const bf16x8*)(H2t + ncol*64 + (((4+g) ^ (ncol&7))<<3)), bh);
    sna = MFMA(pa0, vnf0, sna);
    sna = MFMA(pa1, vnf1, sna);
    if (nw < 2) {
      av = MFMA(pa0, *(const bf16x8*)(uCt + ncol*64 + (((g  ) ^ (ncol&7))<<3)), av);
      av = MFMA(pa1, *(const bf16x8*)(uCt + ncol*64 + (((4+g) ^ (ncol&7))<<3)), av);
    }
    __syncthreads();  // D: P-stage reads done
  }

  // ---- write distributed state (no cross-wave merge needed) ----
  float* BhL = (float*)(Lds + 0);
  float* snL = (float*)(Lds + 4096);
  float* avL = (float*)(Lds + 8192);
  float* asB = (float*)(Lds + 8960);
  float* o1  = (float*)(Lds + 9472);
  float* o2  = (float*)(Lds + 9984);

  if (g < 2) {
#pragma unroll
    for (int i = 0; i < 4; ++i) {
      BhL[(g*4+i)*128 + ncol] = bh[i];
      snL[(g*4+i)*128 + ncol] = sna[i];
    }
  } else if (nw < 2) {
#pragma unroll
    for (int i = 0; i < 4; ++i) {
      if (ncol < 24) avL[((g-2)*4+i)*24 + ncol] = av[i];
    }
  }
  if (nw == 0 && c == 0 && g < 2) {
#pragma unroll
    for (int i = 0; i < 4; ++i) DhL[hb + i] = drun[i];
  }
  __syncthreads();

  // equivariant output
  if (tid >= 192 && tid < 216) {
    const int t = tid - 192, vv = t/3;
    out[r*24 + t] = pos[r*24 + t] + 1.7320508076f * avL[vv*24 + t] / DhL[vv];
  }
  // agg_s
  if (tid < 128) {
    const int j = tid, hh = j >> 4;
    float ev = 0.f;
#pragma unroll 4
    for (int m = 0; m < 128; ++m)
      ev = fmaf(BhL[hh*128 + m], Wev[m*128 + j], ev);
    asB[j] = (snL[hh*128 + j] + ev) / DhL[hh];
  }
  __syncthreads();
  if (tid < 128) {
    const int j = tid;
    float acc = bo0[j];
#pragma unroll 4
    for (int i = 0; i < 128; ++i) acc = fmaf(asB[i], Wo0[i*128 + j], acc);
    o1[j] = fsilu(acc);
  }
  __syncthreads();
  if (tid < 128) {
    const int j = tid;
    float acc = bo1[j];
#pragma unroll 4
    for (int i = 0; i < 128; ++i) acc = fmaf(o1[i], Wo1[i*128 + j], acc);
    o2[j] = fsilu(acc);
  }
  __syncthreads();
  if (tid < 128) {
    const int j = tid;
    float acc = bo2[j];
#pragma unroll 4
    for (int i = 0; i < 128; ++i) acc = fmaf(o2[i], Wo2[i*128 + j], acc);
    out[12288 + r*128 + j] = feat[r*128 + j] + acc;
  }
}

extern "C" void kernel_launch(void* const* d_in, const int* in_sizes, int n_in,
                              void* d_out, int out_size, void* d_ws, size_t ws_size,
                              hipStream_t stream)
{
  const float* pos  = (const float*)d_in[0];
  const float* feat = (const float*)d_in[1];
  const float* We0  = (const float*)d_in[2];
  const float* be0  = (const float*)d_in[3];
  const float* We1  = (const float*)d_in[4];
  const float* be1  = (const float*)d_in[5];
  const float* Wq   = (const float*)d_in[6];
  const float* Wk   = (const float*)d_in[7];
  const float* Wek  = (const float*)d_in[8];
  const float* Wv   = (const float*)d_in[9];
  const float* Wev  = (const float*)d_in[10];
  const float* Wg   = (const float*)d_in[11];
  const float* Wo0  = (const float*)d_in[12];
  const float* bo0  = (const float*)d_in[13];
  const float* Wo1  = (const float*)d_in[14];
  const float* bo1  = (const float*)d_in[15];
  const float* Wo2  = (const float*)d_in[16];
  const float* bo2  = (const float*)d_in[17];
  float* ws  = (float*)d_ws;
  float* out = (float*)d_out;

  hipLaunchKernelGGL(k_nodeprep, dim3(512), dim3(128), 0, stream,
                     feat, Wq, Wk, Wv, Wek, Wg, ws);
  hipLaunchKernelGGL(k_lbase, dim3(512), dim3(512), 0, stream, ws);
  hipLaunchKernelGGL(k_wprep, dim3(96), dim3(256), 0, stream, We0, We1, ws);
  hipLaunchKernelGGL(k_edge4, dim3(512), dim3(512), 0, stream,
                     pos, feat, be0, be1, Wev,
                     Wo0, bo0, Wo1, bo1, Wo2, bo2, ws, out);
}

// Round 5
// 136.473 us; speedup vs baseline: 3.3125x; 1.1030x over previous
//
#include <hip/hip_runtime.h>
#include <hip/hip_bf16.h>

// EnTransformerBlock, MFMA v5: 4 barriers/tile, pipelined geometry,
// hw bf16 cvt, rcp-based silu. N=512, V=8, F=128, H=8, FH=16, B=8.
//
// ws layout (float offsets):
//   kn    @ 0         f32 [512][128]
//   qn    @ 65536     f32 [512][128]
//   Lb    @ 131072    f32 [512][512][8]   (q.k per head, pre-divided by 4)
//   vnT   @ 2228224   bf16[128][512]      (feat@Wv transposed)
//   AWgT  @ 2260992   bf16[512][16][128]  (rows 0-7: Wek-folded-q /4; 8-15: Wg^T)
//   W0T   @ 2785280   bf16[128][64]       (We0 transposed)
//   W1T   @ 2789376   bf16[128][128]      (We1 transposed)

#define WS_KN   0
#define WS_QN   65536
#define WS_LB   131072
#define WS_VNT  2228224
#define WS_AWGT 2260992
#define WS_W0T  2785280
#define WS_W1T  2789376

typedef short bf16x8 __attribute__((ext_vector_type(8)));
typedef short short4v __attribute__((ext_vector_type(4)));
typedef float f32x4 __attribute__((ext_vector_type(4)));

static __device__ __forceinline__ unsigned short f2b(float x) {
  __hip_bfloat16 h = __float2bfloat16(x);
  return reinterpret_cast<unsigned short&>(h);
}
static __device__ __forceinline__ unsigned pk2(float a, float b) {
  __hip_bfloat162 t = __float22bfloat162_rn(make_float2(a, b));
  return reinterpret_cast<unsigned&>(t);
}
static __device__ __forceinline__ float fsilu(float x) {
  return x * __builtin_amdgcn_rcpf(1.f + __expf(-x));
}

__global__ __launch_bounds__(128) void k_nodeprep(
    const float* __restrict__ feat, const float* __restrict__ Wq,
    const float* __restrict__ Wk, const float* __restrict__ Wv,
    const float* __restrict__ Wek, const float* __restrict__ Wg,
    float* __restrict__ ws)
{
  const int r = blockIdx.x, j = threadIdx.x;
  __shared__ float fr[128];
  __shared__ float qL[128];
  fr[j] = feat[r*128 + j];
  __syncthreads();
  float aq = 0.f, ak = 0.f, av = 0.f;
#pragma unroll 4
  for (int i = 0; i < 128; ++i) {
    const float f = fr[i];
    aq = fmaf(f, Wq[i*128 + j], aq);
    ak = fmaf(f, Wk[i*128 + j], ak);
    av = fmaf(f, Wv[i*128 + j], av);
  }
  ws[WS_QN + r*128 + j] = aq;
  ws[WS_KN + r*128 + j] = ak;
  unsigned short* vnT = (unsigned short*)(ws + WS_VNT);
  vnT[j*512 + r] = f2b(av);
  qL[j] = aq;
  __syncthreads();
  unsigned short* AW = (unsigned short*)(ws + WS_AWGT) + r*2048;
  const float* wr = Wek + j*128;
#pragma unroll
  for (int h = 0; h < 8; ++h) {
    float acc = 0.f;
#pragma unroll
    for (int f = 0; f < 16; ++f)
      acc = fmaf(wr[16*h + f], qL[16*h + f], acc);
    AW[h*128 + j] = f2b(acc * 0.25f);
  }
#pragma unroll
  for (int v = 0; v < 8; ++v)
    AW[(8 + v)*128 + j] = f2b(Wg[j*8 + v]);
}

__global__ __launch_bounds__(512) void k_lbase(float* __restrict__ ws)
{
  const int r = blockIdx.x, s = threadIdx.x;
  __shared__ float qL[128];
  if (s < 128) qL[s] = ws[WS_QN + r*128 + s];
  __syncthreads();
  const float* knr = ws + s*128;
  float* Lb = ws + WS_LB + (r*512 + s)*8;
#pragma unroll
  for (int h = 0; h < 8; ++h) {
    float acc = 0.f;
#pragma unroll
    for (int f = 0; f < 16; ++f)
      acc = fmaf(knr[16*h + f], qL[16*h + f], acc);
    Lb[h] = acc * 0.25f;
  }
}

__global__ __launch_bounds__(256) void k_wprep(
    const float* __restrict__ We0, const float* __restrict__ We1,
    float* __restrict__ ws)
{
  const int i = blockIdx.x*256 + threadIdx.x;
  unsigned short* W0T = (unsigned short*)(ws + WS_W0T);
  unsigned short* W1T = (unsigned short*)(ws + WS_W1T);
  if (i < 8192) {
    const int n = i >> 6, k = i & 63;
    W0T[n*64 + k] = f2b(We0[k*128 + n]);
  } else if (i < 24576) {
    const int t = i - 8192, n = t >> 7, k = t & 127;
    W1T[n*128 + k] = f2b(We1[k*128 + n]);
  }
}

// Block LDS map (bytes):
//   Es   @ 0      2 x bf16[64][64]  16384  (8-blk XOR swizzle, dbuf)
//   H1   @ 16384  bf16[64][128]     16384  (16-blk XOR swizzle)
//   H2r  @ 32768  bf16[64][128]     16384  (16-blk swizzle)
//   H2t  @ 49152  bf16[128][64]     16384  (8-blk swizzle)
//   uCt  @ 65536  2 x bf16[32][64]   8192  (8-blk swizzle, dbuf; rows 24-31 zero)
//   Pb   @ 73728  bf16[16][64]       2048  (8-blk swizzle)
//   mxL  @ 75776  f32[4][8], wsL @ 75904 f32[4][8], DhL @ 76032 f32[8]
// merge aliases (post-loop): BhL@0, snL@4096, avL@8192, asB@8960, o1@9472, o2@9984

#define MFMA(a,b,c) __builtin_amdgcn_mfma_f32_16x16x32_bf16((a),(b),(c),0,0,0)

__global__ __launch_bounds__(512, 4) void k_edge5(
    const float* __restrict__ pos, const float* __restrict__ feat,
    const float* __restrict__ be0, const float* __restrict__ be1,
    const float* __restrict__ Wev,
    const float* __restrict__ Wo0, const float* __restrict__ bo0,
    const float* __restrict__ Wo1, const float* __restrict__ bo1,
    const float* __restrict__ Wo2, const float* __restrict__ bo2,
    const float* __restrict__ ws, float* __restrict__ out)
{
  __shared__ __align__(16) char Lds[76160];
  const int tid = threadIdx.x;
  const int nw = tid >> 6, l = tid & 63;
  const int r = blockIdx.x;
  const int c = l & 15, g = l >> 4;

  unsigned short* Es  = (unsigned short*)(Lds + 0);
  unsigned short* H1  = (unsigned short*)(Lds + 16384);
  unsigned short* H2r = (unsigned short*)(Lds + 32768);
  unsigned short* H2t = (unsigned short*)(Lds + 49152);
  unsigned short* uCt = (unsigned short*)(Lds + 65536);
  unsigned short* Pb  = (unsigned short*)(Lds + 73728);
  float* mxL = (float*)(Lds + 75776);
  float* wsL = (float*)(Lds + 75904);
  float* DhL = (float*)(Lds + 76032);

  const unsigned short* vnT = (const unsigned short*)(ws + WS_VNT);
  const unsigned short* W0T = (const unsigned short*)(ws + WS_W0T);
  const unsigned short* W1T = (const unsigned short*)(ws + WS_W1T);
  const float* LbG = ws + WS_LB + r*4096;

  // geometry identity: one edge-vector per thread
  const int sl = tid >> 3, v = tid & 7;
  const float prx = pos[r*24 + v*3 + 0];
  const float pry = pos[r*24 + v*3 + 1];
  const float prz = pos[r*24 + v*3 + 2];

  // wave column ownership + loop-invariant weight fragments
  const int ncol = nw*16 + c;
  const float be0v = be0[ncol], be1v = be1[ncol];
  const bf16x8 w0f0 = *(const bf16x8*)(W0T + ncol*64 + g*8);
  const bf16x8 w0f1 = *(const bf16x8*)(W0T + ncol*64 + 32 + g*8);
  bf16x8 w1f[4];
#pragma unroll
  for (int kb = 0; kb < 4; ++kb)
    w1f[kb] = *(const bf16x8*)(W1T + ncol*128 + kb*32 + g*8);
  bf16x8 awf[4];
  if (nw < 4) {
    const unsigned short* AWgG = (const unsigned short*)(ws + WS_AWGT) + r*2048;
#pragma unroll
    for (int kb = 0; kb < 4; ++kb)
      awf[kb] = *(const bf16x8*)(AWgG + c*128 + kb*32 + g*8);
  }

  f32x4 bh = {0,0,0,0}, sna = {0,0,0,0}, av = {0,0,0,0};
  float mrun[4] = {-1e30f,-1e30f,-1e30f,-1e30f};
  float drun[4] = {0.f,0.f,0.f,0.f};
  float mrun_c = -1e30f;
  const int hb = (g & 1)*4;

  // ---- prologue: zero uCt pads (both bufs) + geometry tile 0 -> buf 0 ----
  uCt[1536 + tid] = 0;
  uCt[2048 + 1536 + tid] = 0;
  {
    const float dx = pos[sl*24 + v*3 + 0] - prx;
    const float dy = pos[sl*24 + v*3 + 1] - pry;
    const float dz = pos[sl*24 + v*3 + 2] - prz;
    const float l2 = fmaf(dx,dx, fmaf(dy,dy, fmaf(dz,dz, 1e-20f)));
    const float inv = rsqrtf(l2);
    const float len = l2 * inv;
    uCt[(v*3+0)*64 + (((sl>>3) ^ ((v*3+0)&7))<<3) + (sl&7)] = f2b(dx*inv);
    uCt[(v*3+1)*64 + (((sl>>3) ^ ((v*3+1)&7))<<3) + (sl&7)] = f2b(dy*inv);
    uCt[(v*3+2)*64 + (((sl>>3) ^ ((v*3+2)&7))<<3) + (sl&7)] = f2b(dz*inv);
    const float yy = 2.f - len*0.2f;
    const float env = (yy > 0.f) ? 1.9784655648f * __expf(-__builtin_amdgcn_rcpf(yy)) : 0.f;
    const float coef = 0.4472135955f * env * inv;
    const float arg = len * 0.31415926535f;
    const float s1v = __sinf(arg), c1v = __cosf(arg);
    const float twc = 2.f*c1v;
    float e[8]; float sp = 0.f, sc = s1v;
#pragma unroll
    for (int b = 0; b < 8; ++b) { e[b] = coef*sc; const float nx = fmaf(twc, sc, -sp); sp = sc; sc = nx; }
    union { bf16x8 v8; unsigned u4[4]; } pk;
#pragma unroll
    for (int q = 0; q < 4; ++q) pk.u4[q] = pk2(e[2*q], e[2*q+1]);
    *(bf16x8*)(Es + sl*64 + ((v ^ (sl&7))<<3)) = pk.v8;
  }
  __syncthreads();

  for (int it = 0; it < 8; ++it) {
    const int sbase = it << 6;
    const int cur = it & 1, nxt = cur ^ 1;
    const unsigned short* EsC  = Es + cur*4096;
    const unsigned short* uCtC = uCt + cur*2048;

    // ---- prefetches (global, consumed later) ----
    const bf16x8 vnf0 = *(const bf16x8*)(vnT + ncol*512 + sbase + g*8);
    const bf16x8 vnf1 = *(const bf16x8*)(vnT + ncol*512 + sbase + 32 + g*8);
    float lbp[4] = {0.f,0.f,0.f,0.f};
    if (nw < 4 && c < 8) {
#pragma unroll
      for (int i = 0; i < 4; ++i)
        lbp[i] = LbG[(sbase + nw*16 + g*4 + i)*8 + c];
    }
    float npx = 0.f, npy = 0.f, npz = 0.f;
    if (it < 7) {
      const int sg = sbase + 64 + sl;
      npx = pos[sg*24 + v*3 + 0];
      npy = pos[sg*24 + v*3 + 1];
      npz = pos[sg*24 + v*3 + 2];
    }

    // ---- L0: Es[64][64] @ We0 -> H1 ----
    {
      f32x4 a0[4];
#pragma unroll
      for (int m = 0; m < 4; ++m) {
        const int ra = m*16 + c;
        const bf16x8 e0 = *(const bf16x8*)(EsC + ra*64 + (((g  ) ^ (ra&7))<<3));
        const bf16x8 e1 = *(const bf16x8*)(EsC + ra*64 + (((4+g) ^ (ra&7))<<3));
        f32x4 acc = {0,0,0,0};
        acc = MFMA(e0, w0f0, acc);
        acc = MFMA(e1, w0f1, acc);
        a0[m] = acc;
      }
#pragma unroll
      for (int m = 0; m < 4; ++m)
#pragma unroll
        for (int i = 0; i < 4; ++i) {
          const int row = m*16 + g*4 + i;
          H1[row*128 + (((ncol>>3) ^ (row&15))<<3) + (c&7)] =
              f2b(fsilu(a0[m][i] + be0v));
        }
    }

    // ---- geometry for tile it+1 -> nxt buffers (overlaps; ordered by B..s2) ----
    if (it < 7) {
      const float dx = npx - prx, dy = npy - pry, dz = npz - prz;
      const float l2 = fmaf(dx,dx, fmaf(dy,dy, fmaf(dz,dz, 1e-20f)));
      const float inv = rsqrtf(l2);
      const float len = l2 * inv;
      unsigned short* uCtN = uCt + nxt*2048;
      uCtN[(v*3+0)*64 + (((sl>>3) ^ ((v*3+0)&7))<<3) + (sl&7)] = f2b(dx*inv);
      uCtN[(v*3+1)*64 + (((sl>>3) ^ ((v*3+1)&7))<<3) + (sl&7)] = f2b(dy*inv);
      uCtN[(v*3+2)*64 + (((sl>>3) ^ ((v*3+2)&7))<<3) + (sl&7)] = f2b(dz*inv);
      const float yy = 2.f - len*0.2f;
      const float env = (yy > 0.f) ? 1.9784655648f * __expf(-__builtin_amdgcn_rcpf(yy)) : 0.f;
      const float coef = 0.4472135955f * env * inv;
      const float arg = len * 0.31415926535f;
      const float s1v = __sinf(arg), c1v = __cosf(arg);
      const float twc = 2.f*c1v;
      float e[8]; float sp = 0.f, sc = s1v;
#pragma unroll
      for (int b = 0; b < 8; ++b) { e[b] = coef*sc; const float nx = fmaf(twc, sc, -sp); sp = sc; sc = nx; }
      union { bf16x8 v8; unsigned u4[4]; } pk;
#pragma unroll
      for (int q = 0; q < 4; ++q) pk.u4[q] = pk2(e[2*q], e[2*q+1]);
      *(bf16x8*)(Es + nxt*4096 + sl*64 + ((v ^ (sl&7))<<3)) = pk.v8;
    }
    __syncthreads();  // B: H1 ready

    // ---- L1: H1[64][128] @ We1 -> H2r + H2t ----
    {
      f32x4 a1[4];
#pragma unroll
      for (int m = 0; m < 4; ++m) {
        const int ra = m*16 + c;
        f32x4 acc = {0,0,0,0};
#pragma unroll
        for (int kb = 0; kb < 4; ++kb) {
          const bf16x8 af = *(const bf16x8*)(H1 + ra*128 + (((kb*4+g) ^ (ra&15))<<3));
          acc = MFMA(af, w1f[kb], acc);
        }
        a1[m] = acc;
      }
#pragma unroll
      for (int m = 0; m < 4; ++m) {
        unsigned short bv[4];
#pragma unroll
        for (int i = 0; i < 4; ++i) {
          const int row = m*16 + g*4 + i;
          bv[i] = f2b(fsilu(a1[m][i] + be1v));
          H2r[row*128 + (((ncol>>3) ^ (row&15))<<3) + (c&7)] = bv[i];
        }
        short4v pk;
        pk[0] = (short)bv[0]; pk[1] = (short)bv[1];
        pk[2] = (short)bv[2]; pk[3] = (short)bv[3];
        *(short4v*)(H2t + ncol*64 + ((((m<<1)+(g>>1)) ^ (ncol&7))<<3) + ((g&1)<<2)) = pk;
      }
    }
    __syncthreads();  // C: H2r/H2t ready

    // ---- LG + tile submax (waves 0-3, 16 senders each) ----
    float lgv[4];
    if (nw < 4) {
      const int ra = nw*16 + c;
      f32x4 acc = {0,0,0,0};
#pragma unroll
      for (int kb = 0; kb < 4; ++kb) {
        const bf16x8 af = *(const bf16x8*)(H2r + ra*128 + (((kb*4+g) ^ (ra&15))<<3));
        acc = MFMA(af, awf[kb], acc);
      }
#pragma unroll
      for (int i = 0; i < 4; ++i) lgv[i] = acc[i];
      if (c < 8) {
#pragma unroll
        for (int i = 0; i < 4; ++i) {
          const int srow = nw*16 + g*4 + i;
          lgv[i] += lbp[i];
          if (sbase + srow == r) lgv[i] = -1e30f;
        }
      }
      float t = fmaxf(fmaxf(lgv[0], lgv[1]), fmaxf(lgv[2], lgv[3]));
      t = fmaxf(t, __shfl_xor(t, 16));
      t = fmaxf(t, __shfl_xor(t, 32));
      if (g == 0 && c < 8) mxL[nw*8 + c] = t;
    }
    __syncthreads();  // s1: mxL ready

    // ---- all waves: rescale factors ----
    float rsc[4];
#pragma unroll
    for (int i = 0; i < 4; ++i) {
      const int h = hb + i;
      const float tm = fmaxf(fmaxf(mxL[h], mxL[8+h]), fmaxf(mxL[16+h], mxL[24+h]));
      const float mnew = fmaxf(mrun[i], tm);
      rsc[i] = __expf(mrun[i] - mnew);
      mrun[i] = mnew;
    }
    // ---- owners: P values + wsum ----
    if (nw < 4) {
      const int hc = c & 7;
      const float tmc = fmaxf(fmaxf(mxL[hc], mxL[8+hc]), fmaxf(mxL[16+hc], mxL[24+hc]));
      mrun_c = fmaxf(mrun_c, tmc);
      float val[4], wsp = 0.f;
#pragma unroll
      for (int i = 0; i < 4; ++i) { val[i] = __expf(lgv[i] - mrun_c); wsp += val[i]; }
      wsp += __shfl_xor(wsp, 16);
      wsp += __shfl_xor(wsp, 32);
      if (g == 0 && c < 8) wsL[nw*8 + c] = wsp;
      float fin[4];
#pragma unroll
      for (int i = 0; i < 4; ++i) {
        const float oth = __shfl_xor(val[i], 8);
        fin[i] = (c < 8) ? val[i] : oth * lgv[i];
      }
      short4v pkp;
      const unsigned p01 = pk2(fin[0], fin[1]);
      const unsigned p23 = pk2(fin[2], fin[3]);
      pkp[0] = (short)(p01 & 0xffff); pkp[1] = (short)(p01 >> 16);
      pkp[2] = (short)(p23 & 0xffff); pkp[3] = (short)(p23 >> 16);
      *(short4v*)(Pb + c*64 + ((((nw<<1)+(g>>1)) ^ (c&7))<<3) + ((g&1)<<2)) = pkp;
    }
    __syncthreads();  // s2: Pb/wsL ready

    // ---- all waves: drun, rescale, P-MFMAs ----
#pragma unroll
    for (int i = 0; i < 4; ++i) {
      const int h = hb + i;
      drun[i] = drun[i]*rsc[i] + (wsL[h] + wsL[8+h] + wsL[16+h] + wsL[24+h]);
      bh[i] *= rsc[i]; sna[i] *= rsc[i]; av[i] *= rsc[i];
    }
    const bf16x8 pa0 = *(const bf16x8*)(Pb + c*64 + (((g  ) ^ (c&7))<<3));
    const bf16x8 pa1 = *(const bf16x8*)(Pb + c*64 + (((4+g) ^ (c&7))<<3));
    bh = MFMA(pa0, *(const bf16x8*)(H2t + ncol*64 + (((g  ) ^ (ncol&7))<<3)), bh);
    bh = MFMA(pa1, *(const bf16x8*)(H2t + ncol*64 + (((4+g) ^ (ncol&7))<<3)), bh);
    sna = MFMA(pa0, vnf0, sna);
    sna = MFMA(pa1, vnf1, sna);
    if (nw == 4 || nw == 5) {
      const int nc2 = (nw - 4)*16 + c;
      av = MFMA(pa0, *(const bf16x8*)(uCtC + nc2*64 + (((g  ) ^ (nc2&7))<<3)), av);
      av = MFMA(pa1, *(const bf16x8*)(uCtC + nc2*64 + (((4+g) ^ (nc2&7))<<3)), av);
    }
    // no barrier: next-tile buffers are the other halves; reuse ordered by B/C/s1/s2
  }

  __syncthreads();

  // ---- distributed state -> LDS merge buffers ----
  float* BhL = (float*)(Lds + 0);
  float* snL = (float*)(Lds + 4096);
  float* avL = (float*)(Lds + 8192);
  float* asB = (float*)(Lds + 8960);
  float* o1  = (float*)(Lds + 9472);
  float* o2  = (float*)(Lds + 9984);

  if (g < 2) {
#pragma unroll
    for (int i = 0; i < 4; ++i) {
      BhL[(g*4+i)*128 + ncol] = bh[i];
      snL[(g*4+i)*128 + ncol] = sna[i];
    }
  }
  if ((nw == 4 || nw == 5) && g >= 2) {
    const int nc2 = (nw - 4)*16 + c;
    if (nc2 < 24) {
#pragma unroll
      for (int i = 0; i < 4; ++i)
        avL[((g-2)*4+i)*24 + nc2] = av[i];
    }
  }
  if (nw == 0 && c == 0 && g < 2) {
#pragma unroll
    for (int i = 0; i < 4; ++i) DhL[hb + i] = drun[i];
  }
  __syncthreads();

  // equivariant output
  if (tid >= 192 && tid < 216) {
    const int t = tid - 192, vv = t/3;
    out[r*24 + t] = pos[r*24 + t]
        + 1.7320508076f * avL[vv*24 + t] * __builtin_amdgcn_rcpf(DhL[vv]);
  }
  // agg_s
  if (tid < 128) {
    const int j = tid, hh = j >> 4;
    float ev = 0.f;
#pragma unroll 4
    for (int m = 0; m < 128; ++m)
      ev = fmaf(BhL[hh*128 + m], Wev[m*128 + j], ev);
    asB[j] = (snL[hh*128 + j] + ev) * __builtin_amdgcn_rcpf(DhL[hh]);
  }
  __syncthreads();
  if (tid < 128) {
    const int j = tid;
    float acc = bo0[j];
#pragma unroll 4
    for (int i = 0; i < 128; ++i) acc = fmaf(asB[i], Wo0[i*128 + j], acc);
    o1[j] = fsilu(acc);
  }
  __syncthreads();
  if (tid < 128) {
    const int j = tid;
    float acc = bo1[j];
#pragma unroll 4
    for (int i = 0; i < 128; ++i) acc = fmaf(o1[i], Wo1[i*128 + j], acc);
    o2[j] = fsilu(acc);
  }
  __syncthreads();
  if (tid < 128) {
    const int j = tid;
    float acc = bo2[j];
#pragma unroll 4
    for (int i = 0; i < 128; ++i) acc = fmaf(o2[i], Wo2[i*128 + j], acc);
    out[12288 + r*128 + j] = feat[r*128 + j] + acc;
  }
}

extern "C" void kernel_launch(void* const* d_in, const int* in_sizes, int n_in,
                              void* d_out, int out_size, void* d_ws, size_t ws_size,
                              hipStream_t stream)
{
  const float* pos  = (const float*)d_in[0];
  const float* feat = (const float*)d_in[1];
  const float* We0  = (const float*)d_in[2];
  const float* be0  = (const float*)d_in[3];
  const float* We1  = (const float*)d_in[4];
  const float* be1  = (const float*)d_in[5];
  const float* Wq   = (const float*)d_in[6];
  const float* Wk   = (const float*)d_in[7];
  const float* Wek  = (const float*)d_in[8];
  const float* Wv   = (const float*)d_in[9];
  const float* Wev  = (const float*)d_in[10];
  const float* Wg   = (const float*)d_in[11];
  const float* Wo0  = (const float*)d_in[12];
  const float* bo0  = (const float*)d_in[13];
  const float* Wo1  = (const float*)d_in[14];
  const float* bo1  = (const float*)d_in[15];
  const float* Wo2  = (const float*)d_in[16];
  const float* bo2  = (const float*)d_in[17];
  float* ws  = (float*)d_ws;
  float* out = (float*)d_out;

  hipLaunchKernelGGL(k_nodeprep, dim3(512), dim3(128), 0, stream,
                     feat, Wq, Wk, Wv, Wek, Wg, ws);
  hipLaunchKernelGGL(k_lbase, dim3(512), dim3(512), 0, stream, ws);
  hipLaunchKernelGGL(k_wprep, dim3(96), dim3(256), 0, stream, We0, We1, ws);
  hipLaunchKernelGGL(k_edge5, dim3(512), dim3(512), 0, stream,
                     pos, feat, be0, be1, Wev,
                     Wo0, bo0, Wo1, bo1, Wo2, bo2, ws, out);
}